// Round 3
// baseline (13918.715 us; speedup 1.0000x reference)
//
#include <hip/hip_runtime.h>
#include <cstdint>

#define HIDDEN  128
#define NLAYERS 6
#define NNODES  50000
#define NEDGES  640000

typedef short short8 __attribute__((ext_vector_type(8)));
typedef float f32x4  __attribute__((ext_vector_type(4)));

// ---- bf16 <-> f32 helpers (RNE) -------------------------------------------
__device__ __forceinline__ float bf2f(unsigned short u) {
    return __uint_as_float(((unsigned int)u) << 16);
}
__device__ __forceinline__ unsigned short f2bf(float f) {
    unsigned int u = __float_as_uint(f);
    unsigned int r = u + 0x7FFFu + ((u >> 16) & 1u);   // round-nearest-even
    return (unsigned short)(r >> 16);
}
__device__ __forceinline__ unsigned int pack2(float a, float b) {
    return (unsigned int)f2bf(a) | ((unsigned int)f2bf(b) << 16);
}
__device__ __forceinline__ void unpack8(uint4 v, float* f) {
    f[0] = bf2f((unsigned short)(v.x & 0xffff)); f[1] = bf2f((unsigned short)(v.x >> 16));
    f[2] = bf2f((unsigned short)(v.y & 0xffff)); f[3] = bf2f((unsigned short)(v.y >> 16));
    f[4] = bf2f((unsigned short)(v.z & 0xffff)); f[5] = bf2f((unsigned short)(v.z >> 16));
    f[6] = bf2f((unsigned short)(v.w & 0xffff)); f[7] = bf2f((unsigned short)(v.w >> 16));
}

// ---------------------------------------------------------------------------
// Index dtype detection + canonicalization (as in passing round)
// ---------------------------------------------------------------------------
__global__ void detect_kernel(const int* __restrict__ ei, int* __restrict__ flag)
{
    int lane = threadIdx.x;
    int v = ei[2 * lane + 1];
    unsigned long long b = __ballot(v != 0);
    if (lane == 0) *flag = (b != 0ULL) ? 1 : 0;
}

__global__ void normidx_kernel(const int* __restrict__ ei, const int* __restrict__ flag,
                               int* __restrict__ s32, int* __restrict__ d32)
{
    int e = blockIdx.x * blockDim.x + threadIdx.x;
    if (e >= NEDGES) return;
    int s, d;
    if (*flag) { s = ei[e]; d = ei[NEDGES + e]; }
    else       { s = ei[2 * e]; d = ei[2 * (NEDGES + e)]; }
    s32[e] = min(max(s, 0), NNODES - 1);
    d32[e] = min(max(d, 0), NNODES - 1);
}

// ---------------------------------------------------------------------------
// Weight transpose+convert: W [L][K][N] fp32 -> WT [L][N][K] bf16
// ---------------------------------------------------------------------------
__global__ void transpose_kernel(const float* __restrict__ W, unsigned short* __restrict__ WT,
                                 int K, int N, int L)
{
    long idx = (long)blockIdx.x * 256 + threadIdx.x;
    long tot = (long)L * K * N;
    if (idx >= tot) return;
    int kn = (int)(idx % ((long)K * N));
    int l  = (int)(idx / ((long)K * N));
    int k = kn / N;
    int n = kn % N;
    WT[(long)l * K * N + (long)n * K + k] = f2bf(W[idx]);
}

// ---------------------------------------------------------------------------
// Encoder (bf16 out)
// ---------------------------------------------------------------------------
__global__ void encode_kernel(const float* __restrict__ ea,
                              const float* __restrict__ w,
                              const float* __restrict__ b,
                              unsigned short* __restrict__ ef)
{
    int idx = blockIdx.x * blockDim.x + threadIdx.x;
    int e = idx >> 5;
    if (e >= NEDGES) return;
    int j = (idx & 31) << 2;
    float a0 = ea[e * 3 + 0], a1 = ea[e * 3 + 1], a2 = ea[e * 3 + 2];
    float4 w0 = *(const float4*)(w + 0 * HIDDEN + j);
    float4 w1 = *(const float4*)(w + 1 * HIDDEN + j);
    float4 w2 = *(const float4*)(w + 2 * HIDDEN + j);
    float4 bb = *(const float4*)(b + j);
    ushort4 o;
    o.x = f2bf(fmaf(a0, w0.x, fmaf(a1, w1.x, fmaf(a2, w2.x, bb.x))));
    o.y = f2bf(fmaf(a0, w0.y, fmaf(a1, w1.y, fmaf(a2, w2.y, bb.y))));
    o.z = f2bf(fmaf(a0, w0.z, fmaf(a1, w1.z, fmaf(a2, w2.z, bb.z))));
    o.w = f2bf(fmaf(a0, w0.w, fmaf(a1, w1.w, fmaf(a2, w2.w, bb.w))));
    *(ushort4*)(ef + (long)e * HIDDEN + j) = o;
}

__global__ void count_kernel(const int* __restrict__ dst, float* __restrict__ cnt)
{
    int e = blockIdx.x * blockDim.x + threadIdx.x;
    if (e < NEDGES) atomicAdd(&cnt[dst[e]], 1.0f);
}

// ---------------------------------------------------------------------------
// MFMA edge layer. 64 edges x 128 out per block, 4 waves (16 rows each).
// GEMM1 K=384 (x[dst]|x[src]|ef), GEMM2 K=128, all bf16 operands, fp32 acc.
// A/B LDS row stride 40 elem (80 B: 16B-aligned rows); Hs stride 136 (272 B).
// ---------------------------------------------------------------------------
__global__ __launch_bounds__(256, 4)
void edge_layer_mfma(const float* __restrict__ x,
                     unsigned short* __restrict__ ef,
                     float* __restrict__ sums,
                     const int* __restrict__ src,
                     const int* __restrict__ dst,
                     const unsigned short* __restrict__ W1T,  // [128][384] bf16
                     const float* __restrict__ b1,
                     const unsigned short* __restrict__ W2T,  // [128][128] bf16
                     const float* __restrict__ b2)
{
    __shared__ __align__(16) unsigned short As[64 * 40];
    __shared__ __align__(16) unsigned short Bs[128 * 40];
    __shared__ __align__(16) unsigned short Hs[64 * 136];
    __shared__ int sIdx0[64];
    __shared__ int sIdx1[64];

    const int tid = threadIdx.x;
    const long eb = (long)blockIdx.x * 64;
    if (tid < 64)        sIdx0[tid]      = dst[eb + tid];
    else if (tid < 128)  sIdx1[tid - 64] = src[eb + tid - 64];

    const int lane = tid & 63;
    const int wv   = tid >> 6;
    const int mn   = lane & 15;
    const int q    = lane >> 4;
    const int srow = tid >> 2;          // staging row 0..63
    const int sseg = tid & 3;           // 8-elem segment
    const int bn   = tid >> 1;          // 0..127
    const int bk   = (tid & 1) << 4;    // 0 or 16

    __syncthreads();

    f32x4 acc[8];
#pragma unroll
    for (int t = 0; t < 8; ++t) acc[t] = (f32x4)0.0f;

    // ---- GEMM1: 12 k-steps of 32 ----
    for (int c = 0; c < 12; ++c) {
        if (c < 8) {
            const int* sI = (c < 4) ? sIdx0 : sIdx1;
            const float* sp = x + (long)sI[srow] * HIDDEN + ((c & 3) << 5) + (sseg << 3);
            float4 v0 = *(const float4*)sp;
            float4 v1 = *(const float4*)(sp + 4);
            uint4 w;
            w.x = pack2(v0.x, v0.y); w.y = pack2(v0.z, v0.w);
            w.z = pack2(v1.x, v1.y); w.w = pack2(v1.z, v1.w);
            *(uint4*)&As[srow * 40 + (sseg << 3)] = w;
        } else {
            const unsigned short* sp = ef + (eb + srow) * HIDDEN + ((c - 8) << 5) + (sseg << 3);
            *(uint4*)&As[srow * 40 + (sseg << 3)] = *(const uint4*)sp;
        }
        {
            const unsigned short* wp = W1T + (long)bn * 384 + (c << 5) + bk;
            uint4 a0 = *(const uint4*)wp;
            uint4 a1 = *(const uint4*)(wp + 8);
            *(uint4*)&Bs[bn * 40 + bk]     = a0;
            *(uint4*)&Bs[bn * 40 + bk + 8] = a1;
        }
        __syncthreads();
        short8 af = *(short8*)&As[(wv * 16 + mn) * 40 + (q << 3)];
#pragma unroll
        for (int nt = 0; nt < 8; ++nt) {
            short8 bf = *(short8*)&Bs[(nt * 16 + mn) * 40 + (q << 3)];
            acc[nt] = __builtin_amdgcn_mfma_f32_16x16x32_bf16(af, bf, acc[nt], 0, 0, 0);
        }
        __syncthreads();
    }

    // ---- H = relu(acc + b1) -> Hs bf16 ----
#pragma unroll
    for (int nt = 0; nt < 8; ++nt) {
        float b1v = b1[nt * 16 + mn];
#pragma unroll
        for (int r = 0; r < 4; ++r) {
            float hv = fmaxf(acc[nt][r] + b1v, 0.0f);
            Hs[(wv * 16 + q * 4 + r) * 136 + nt * 16 + mn] = f2bf(hv);
        }
    }
    __syncthreads();

    // ---- GEMM2: 4 k-steps of 32 ----
    f32x4 acc2[8];
#pragma unroll
    for (int t = 0; t < 8; ++t) acc2[t] = (f32x4)0.0f;
    for (int c = 0; c < 4; ++c) {
        {
            const unsigned short* wp = W2T + (long)bn * 128 + (c << 5) + bk;
            uint4 a0 = *(const uint4*)wp;
            uint4 a1 = *(const uint4*)(wp + 8);
            *(uint4*)&Bs[bn * 40 + bk]     = a0;
            *(uint4*)&Bs[bn * 40 + bk + 8] = a1;
        }
        __syncthreads();
        short8 af = *(short8*)&Hs[(wv * 16 + mn) * 136 + (c << 5) + (q << 3)];
#pragma unroll
        for (int nt = 0; nt < 8; ++nt) {
            short8 bf = *(short8*)&Bs[(nt * 16 + mn) * 40 + (q << 3)];
            acc2[nt] = __builtin_amdgcn_mfma_f32_16x16x32_bf16(af, bf, acc2[nt], 0, 0, 0);
        }
        __syncthreads();
    }

    // ---- m = acc2 + b2 -> Hs bf16 (wave-private rows; no barrier hazard) ----
#pragma unroll
    for (int nt = 0; nt < 8; ++nt) {
        float b2v = b2[nt * 16 + mn];
#pragma unroll
        for (int r = 0; r < 4; ++r) {
            Hs[(wv * 16 + q * 4 + r) * 136 + nt * 16 + mn] = f2bf(acc2[nt][r] + b2v);
        }
    }
    __syncthreads();

    // ---- cooperative, coalesced: ef += m ; sums[dst] += m ----
    {
        const int d = sIdx0[srow];
        float* sp = sums + (long)d * HIDDEN;
        unsigned short* ep = ef + (eb + srow) * HIDDEN;
#pragma unroll
        for (int i = 0; i < 4; ++i) {
            int col = (sseg << 3) + (i << 5);
            uint4 mh = *(uint4*)&Hs[srow * 136 + col];
            uint4 eo = *(const uint4*)(ep + col);
            float m[8], e[8];
            unpack8(mh, m);
            unpack8(eo, e);
            uint4 nw;
            nw.x = pack2(e[0] + m[0], e[1] + m[1]);
            nw.y = pack2(e[2] + m[2], e[3] + m[3]);
            nw.z = pack2(e[4] + m[4], e[5] + m[5]);
            nw.w = pack2(e[6] + m[6], e[7] + m[7]);
            *(uint4*)(ep + col) = nw;
#pragma unroll
            for (int j = 0; j < 8; ++j) atomicAdd(sp + col + j, m[j]);
        }
    }
}

// ---------------------------------------------------------------------------
// MFMA node layer. 64 nodes x 128 out per block.
// GEMM1 K=256 (x | sums*cInv), GEMM2 K=128. Residual added in exact fp32.
// ---------------------------------------------------------------------------
__global__ __launch_bounds__(256, 4)
void node_layer_mfma(float* __restrict__ x,
                     const float* __restrict__ sums,
                     const float* __restrict__ cnt,
                     const unsigned short* __restrict__ N1T,  // [128][256] bf16
                     const float* __restrict__ b1,
                     const unsigned short* __restrict__ N2T,  // [128][128] bf16
                     const float* __restrict__ b2)
{
    __shared__ __align__(16) unsigned short As[64 * 40];
    __shared__ __align__(16) unsigned short Bs[128 * 40];
    __shared__ __align__(16) unsigned short Hs[64 * 136];
    __shared__ float cInv[64];

    const int tid = threadIdx.x;
    const long n0 = (long)blockIdx.x * 64;
    if (tid < 64) {
        long n = n0 + tid;
        cInv[tid] = (n < NNODES) ? 1.0f / fmaxf(cnt[n], 1.0f) : 0.0f;
    }

    const int lane = tid & 63;
    const int wv   = tid >> 6;
    const int mn   = lane & 15;
    const int q    = lane >> 4;
    const int srow = tid >> 2;
    const int sseg = tid & 3;
    const int bn   = tid >> 1;
    const int bk   = (tid & 1) << 4;

    long nr = n0 + srow;
    if (nr >= NNODES) nr = NNODES - 1;

    __syncthreads();

    f32x4 acc[8];
#pragma unroll
    for (int t = 0; t < 8; ++t) acc[t] = (f32x4)0.0f;

    // ---- GEMM1: 8 k-steps of 32 ----
    for (int c = 0; c < 8; ++c) {
        {
            const float* base = (c < 4) ? x : sums;
            float sc = (c < 4) ? 1.0f : cInv[srow];
            const float* sp = base + nr * HIDDEN + ((c & 3) << 5) + (sseg << 3);
            float4 v0 = *(const float4*)sp;
            float4 v1 = *(const float4*)(sp + 4);
            uint4 w;
            w.x = pack2(v0.x * sc, v0.y * sc); w.y = pack2(v0.z * sc, v0.w * sc);
            w.z = pack2(v1.x * sc, v1.y * sc); w.w = pack2(v1.z * sc, v1.w * sc);
            *(uint4*)&As[srow * 40 + (sseg << 3)] = w;
        }
        {
            const unsigned short* wp = N1T + (long)bn * 256 + (c << 5) + bk;
            uint4 a0 = *(const uint4*)wp;
            uint4 a1 = *(const uint4*)(wp + 8);
            *(uint4*)&Bs[bn * 40 + bk]     = a0;
            *(uint4*)&Bs[bn * 40 + bk + 8] = a1;
        }
        __syncthreads();
        short8 af = *(short8*)&As[(wv * 16 + mn) * 40 + (q << 3)];
#pragma unroll
        for (int nt = 0; nt < 8; ++nt) {
            short8 bf = *(short8*)&Bs[(nt * 16 + mn) * 40 + (q << 3)];
            acc[nt] = __builtin_amdgcn_mfma_f32_16x16x32_bf16(af, bf, acc[nt], 0, 0, 0);
        }
        __syncthreads();
    }

#pragma unroll
    for (int nt = 0; nt < 8; ++nt) {
        float b1v = b1[nt * 16 + mn];
#pragma unroll
        for (int r = 0; r < 4; ++r) {
            float hv = fmaxf(acc[nt][r] + b1v, 0.0f);
            Hs[(wv * 16 + q * 4 + r) * 136 + nt * 16 + mn] = f2bf(hv);
        }
    }
    __syncthreads();

    f32x4 acc2[8];
#pragma unroll
    for (int t = 0; t < 8; ++t) acc2[t] = (f32x4)0.0f;
    for (int c = 0; c < 4; ++c) {
        {
            const unsigned short* wp = N2T + (long)bn * 128 + (c << 5) + bk;
            uint4 a0 = *(const uint4*)wp;
            uint4 a1 = *(const uint4*)(wp + 8);
            *(uint4*)&Bs[bn * 40 + bk]     = a0;
            *(uint4*)&Bs[bn * 40 + bk + 8] = a1;
        }
        __syncthreads();
        short8 af = *(short8*)&Hs[(wv * 16 + mn) * 136 + (c << 5) + (q << 3)];
#pragma unroll
        for (int nt = 0; nt < 8; ++nt) {
            short8 bf = *(short8*)&Bs[(nt * 16 + mn) * 40 + (q << 3)];
            acc2[nt] = __builtin_amdgcn_mfma_f32_16x16x32_bf16(af, bf, acc2[nt], 0, 0, 0);
        }
        __syncthreads();
    }

    // ---- x += acc2 + b2 (exact fp32 residual; scalar coalesced RMW) ----
#pragma unroll
    for (int nt = 0; nt < 8; ++nt) {
        float b2v = b2[nt * 16 + mn];
#pragma unroll
        for (int r = 0; r < 4; ++r) {
            long row = n0 + wv * 16 + q * 4 + r;
            if (row < NNODES) {
                float* p = x + row * HIDDEN + nt * 16 + mn;
                *p += acc2[nt][r] + b2v;
            }
        }
    }
}

// ---------------------------------------------------------------------------
// Decoder + row L2-normalize (one wave per node)
// ---------------------------------------------------------------------------
__global__ void decode_kernel(const float* __restrict__ x,
                              const float* __restrict__ w,
                              const float* __restrict__ b,
                              float* __restrict__ out)
{
    int gid = blockIdx.x * blockDim.x + threadIdx.x;
    int node = gid >> 6;
    int lane = threadIdx.x & 63;
    if (node >= NNODES) return;
    float a0 = 0.f, a1 = 0.f, a2 = 0.f;
#pragma unroll
    for (int k = lane; k < HIDDEN; k += 64) {
        float xv = x[(long)node * HIDDEN + k];
        a0 = fmaf(xv, w[k * 3 + 0], a0);
        a1 = fmaf(xv, w[k * 3 + 1], a1);
        a2 = fmaf(xv, w[k * 3 + 2], a2);
    }
#pragma unroll
    for (int off = 32; off > 0; off >>= 1) {
        a0 += __shfl_down(a0, off);
        a1 += __shfl_down(a1, off);
        a2 += __shfl_down(a2, off);
    }
    if (lane == 0) {
        a0 += b[0]; a1 += b[1]; a2 += b[2];
        float nrm = sqrtf(a0 * a0 + a1 * a1 + a2 * a2);
        float inv = 1.0f / fmaxf(nrm, 1e-12f);
        out[(long)node * 3 + 0] = a0 * inv;
        out[(long)node * 3 + 1] = a1 * inv;
        out[(long)node * 3 + 2] = a2 * inv;
    }
}

// ---------------------------------------------------------------------------
extern "C" void kernel_launch(void* const* d_in, const int* in_sizes, int n_in,
                              void* d_out, int out_size, void* d_ws, size_t ws_size,
                              hipStream_t stream)
{
    const float* edge_attr = (const float*)d_in[1];
    const int*   ei        = (const int*)d_in[2];
    const float* enc_w     = (const float*)d_in[3];
    const float* enc_b     = (const float*)d_in[4];
    const float* dec_w     = (const float*)d_in[5];
    const float* dec_b     = (const float*)d_in[6];
    const float* edge_w1   = (const float*)d_in[7];
    const float* edge_b1   = (const float*)d_in[8];
    const float* edge_w2   = (const float*)d_in[9];
    const float* edge_b2   = (const float*)d_in[10];
    const float* node_w1   = (const float*)d_in[11];
    const float* node_b1   = (const float*)d_in[12];
    const float* node_w2   = (const float*)d_in[13];
    const float* node_b2   = (const float*)d_in[14];

    // workspace layout (bytes), all 16B-aligned:
    char* ws = (char*)d_ws;
    unsigned short* ef  = (unsigned short*)(ws);                  // 163,840,000
    float* x    = (float*)(ws + 163840000L);                      //  25,600,000
    float* sums = (float*)(ws + 189440000L);                      //  25,600,000
    float* cnt  = (float*)(ws + 215040000L);                      //     200,192
    int*   src  = (int*)  (ws + 215240192L);                      //   2,560,000
    int*   dst  = (int*)  (ws + 217800192L);                      //   2,560,000
    int*   flag = (int*)  (ws + 220360192L);                      //          64
    unsigned short* W1T = (unsigned short*)(ws + 220360256L);     //     589,824
    unsigned short* W2T = (unsigned short*)(ws + 220950080L);     //     196,608
    unsigned short* N1T = (unsigned short*)(ws + 221146688L);     //     393,216
    unsigned short* N2T = (unsigned short*)(ws + 221539904L);     //     196,608
    // total ~221.7 MB

    float* out = (float*)d_out;

    hipMemsetAsync(x, 0, (size_t)NNODES * HIDDEN * sizeof(float), stream);
    hipMemsetAsync(cnt, 0, (size_t)50048 * sizeof(float), stream);

    detect_kernel<<<1, 64, 0, stream>>>(ei, flag);
    normidx_kernel<<<(NEDGES + 255) / 256, 256, 0, stream>>>(ei, flag, src, dst);
    count_kernel<<<(NEDGES + 255) / 256, 256, 0, stream>>>(dst, cnt);
    encode_kernel<<<(NEDGES * 32 + 255) / 256, 256, 0, stream>>>(edge_attr, enc_w, enc_b, ef);

    transpose_kernel<<<(6 * 384 * 128 + 255) / 256, 256, 0, stream>>>(edge_w1, W1T, 384, 128, 6);
    transpose_kernel<<<(6 * 128 * 128 + 255) / 256, 256, 0, stream>>>(edge_w2, W2T, 128, 128, 6);
    transpose_kernel<<<(6 * 256 * 128 + 255) / 256, 256, 0, stream>>>(node_w1, N1T, 256, 128, 6);
    transpose_kernel<<<(6 * 128 * 128 + 255) / 256, 256, 0, stream>>>(node_w2, N2T, 128, 128, 6);

    for (int l = 0; l < NLAYERS; ++l) {
        hipMemsetAsync(sums, 0, (size_t)NNODES * HIDDEN * sizeof(float), stream);
        edge_layer_mfma<<<NEDGES / 64, 256, 0, stream>>>(
            x, ef, sums, src, dst,
            W1T + (long)l * 384 * 128, edge_b1 + (long)l * HIDDEN,
            W2T + (long)l * 128 * 128, edge_b2 + (long)l * HIDDEN);
        node_layer_mfma<<<(NNODES + 63) / 64, 256, 0, stream>>>(
            x, sums, cnt,
            N1T + (long)l * 256 * 128, node_b1 + (long)l * HIDDEN,
            N2T + (long)l * 128 * 128, node_b2 + (long)l * HIDDEN);
    }

    decode_kernel<<<(NNODES * 64 + 255) / 256, 256, 0, stream>>>(x, dec_w, dec_b, out);
}

// Round 4
// 1825.938 us; speedup vs baseline: 7.6228x; 7.6228x over previous
//
#include <hip/hip_runtime.h>
#include <cstdint>

#define HIDDEN  128
#define NLAYERS 6
#define NNODES  50000
#define NEDGES  640000

typedef short short8 __attribute__((ext_vector_type(8)));
typedef float f32x4  __attribute__((ext_vector_type(4)));

// ---- bf16 <-> f32 helpers (RNE) -------------------------------------------
__device__ __forceinline__ float bf2f(unsigned short u) {
    return __uint_as_float(((unsigned int)u) << 16);
}
__device__ __forceinline__ unsigned short f2bf(float f) {
    unsigned int u = __float_as_uint(f);
    unsigned int r = u + 0x7FFFu + ((u >> 16) & 1u);
    return (unsigned short)(r >> 16);
}
__device__ __forceinline__ unsigned int pack2(float a, float b) {
    return (unsigned int)f2bf(a) | ((unsigned int)f2bf(b) << 16);
}
__device__ __forceinline__ void unpack8(uint4 v, float* f) {
    f[0] = bf2f((unsigned short)(v.x & 0xffff)); f[1] = bf2f((unsigned short)(v.x >> 16));
    f[2] = bf2f((unsigned short)(v.y & 0xffff)); f[3] = bf2f((unsigned short)(v.y >> 16));
    f[4] = bf2f((unsigned short)(v.z & 0xffff)); f[5] = bf2f((unsigned short)(v.z >> 16));
    f[6] = bf2f((unsigned short)(v.w & 0xffff)); f[7] = bf2f((unsigned short)(v.w >> 16));
}

// ---------------------------------------------------------------------------
// Index dtype detection + canonicalization
// ---------------------------------------------------------------------------
__global__ void detect_kernel(const int* __restrict__ ei, int* __restrict__ flag)
{
    int lane = threadIdx.x;
    int v = ei[2 * lane + 1];
    unsigned long long b = __ballot(v != 0);
    if (lane == 0) *flag = (b != 0ULL) ? 1 : 0;
}

__global__ void normidx_kernel(const int* __restrict__ ei, const int* __restrict__ flag,
                               int* __restrict__ s32, int* __restrict__ d32)
{
    int e = blockIdx.x * blockDim.x + threadIdx.x;
    if (e >= NEDGES) return;
    int s, d;
    if (*flag) { s = ei[e]; d = ei[NEDGES + e]; }
    else       { s = ei[2 * e]; d = ei[2 * (NEDGES + e)]; }
    s32[e] = min(max(s, 0), NNODES - 1);
    d32[e] = min(max(d, 0), NNODES - 1);
}

__global__ void degree_kernel(const int* __restrict__ dst, int* __restrict__ deg)
{
    int e = blockIdx.x * blockDim.x + threadIdx.x;
    if (e < NEDGES) atomicAdd(&deg[dst[e]], 1);
}

// ---------------------------------------------------------------------------
// Exclusive scan over deg[0..NNODES) -> off, cursor. One 1024-thread block.
// ---------------------------------------------------------------------------
#define SCAN_T 1024
__global__ void scan_kernel(const int* __restrict__ deg, int* __restrict__ off,
                            int* __restrict__ cursor)
{
    __shared__ int part[SCAN_T];
    const int t = threadIdx.x;
    const int CH = (NNODES + SCAN_T - 1) / SCAN_T;
    const int base = t * CH;
    int s = 0;
    for (int i = 0; i < CH; ++i) {
        int idx = base + i;
        if (idx < NNODES) s += deg[idx];
    }
    part[t] = s;
    __syncthreads();
    for (int d = 1; d < SCAN_T; d <<= 1) {
        int v = (t >= d) ? part[t - d] : 0;
        __syncthreads();
        part[t] += v;
        __syncthreads();
    }
    int run = (t == 0) ? 0 : part[t - 1];
    for (int i = 0; i < CH; ++i) {
        int idx = base + i;
        if (idx < NNODES) {
            off[idx] = run;
            cursor[idx] = run;
            run += deg[idx];
        }
    }
    if (t == SCAN_T - 1) off[NNODES] = run;
}

// Scatter edges into dst-sorted positions.
__global__ void scatter_kernel(const int* __restrict__ s32, const int* __restrict__ d32,
                               int* __restrict__ cursor,
                               int* __restrict__ sp, int* __restrict__ dp, int* __restrict__ ep)
{
    int e = blockIdx.x * blockDim.x + threadIdx.x;
    if (e >= NEDGES) return;
    int d = d32[e];
    int p = atomicAdd(&cursor[d], 1);
    sp[p] = s32[e];
    dp[p] = d;
    ep[p] = e;
}

// ---------------------------------------------------------------------------
// Weight transpose+convert: W [L][K][N] fp32 -> WT [L][N][K] bf16
// ---------------------------------------------------------------------------
__global__ void transpose_kernel(const float* __restrict__ W, unsigned short* __restrict__ WT,
                                 int K, int N, int L)
{
    long idx = (long)blockIdx.x * 256 + threadIdx.x;
    long tot = (long)L * K * N;
    if (idx >= tot) return;
    int kn = (int)(idx % ((long)K * N));
    int l  = (int)(idx / ((long)K * N));
    int k = kn / N;
    int n = kn % N;
    WT[(long)l * K * N + (long)n * K + k] = f2bf(W[idx]);
}

// ---------------------------------------------------------------------------
// Encoder into permuted layout: ef[p] = enc(ea[ep[p]])
// ---------------------------------------------------------------------------
__global__ void encode_kernel(const float* __restrict__ ea,
                              const float* __restrict__ w,
                              const float* __restrict__ b,
                              const int* __restrict__ ep,
                              unsigned short* __restrict__ ef)
{
    int idx = blockIdx.x * blockDim.x + threadIdx.x;
    int p = idx >> 5;
    if (p >= NEDGES) return;
    int e = ep[p];
    int j = (idx & 31) << 2;
    float a0 = ea[e * 3 + 0], a1 = ea[e * 3 + 1], a2 = ea[e * 3 + 2];
    float4 w0 = *(const float4*)(w + 0 * HIDDEN + j);
    float4 w1 = *(const float4*)(w + 1 * HIDDEN + j);
    float4 w2 = *(const float4*)(w + 2 * HIDDEN + j);
    float4 bb = *(const float4*)(b + j);
    ushort4 o;
    o.x = f2bf(fmaf(a0, w0.x, fmaf(a1, w1.x, fmaf(a2, w2.x, bb.x))));
    o.y = f2bf(fmaf(a0, w0.y, fmaf(a1, w1.y, fmaf(a2, w2.y, bb.y))));
    o.z = f2bf(fmaf(a0, w0.z, fmaf(a1, w1.z, fmaf(a2, w2.z, bb.z))));
    o.w = f2bf(fmaf(a0, w0.w, fmaf(a1, w1.w, fmaf(a2, w2.w, bb.w))));
    *(ushort4*)(ef + (long)p * HIDDEN + j) = o;
}

// ---------------------------------------------------------------------------
// MFMA edge layer on dst-sorted edges. 64 edges x 128 out per block, 4 waves.
// No per-edge atomics: segmented reduction over dst-runs, one atomic row/run.
// ---------------------------------------------------------------------------
__global__ __launch_bounds__(256, 4)
void edge_layer_mfma(const float* __restrict__ x,
                     unsigned short* __restrict__ ef,
                     float* __restrict__ sums,
                     const int* __restrict__ sp,
                     const int* __restrict__ dp,
                     const unsigned short* __restrict__ W1T,  // [128][384] bf16
                     const float* __restrict__ b1,
                     const unsigned short* __restrict__ W2T,  // [128][128] bf16
                     const float* __restrict__ b2)
{
    __shared__ __align__(16) unsigned short As[64 * 40];
    __shared__ __align__(16) unsigned short Bs[128 * 40];
    __shared__ __align__(16) unsigned short Hs[64 * 136];
    __shared__ int dv[64];
    __shared__ int sv[64];

    const int tid = threadIdx.x;
    const long eb = (long)blockIdx.x * 64;
    if (tid < 64)        dv[tid]      = dp[eb + tid];
    else if (tid < 128)  sv[tid - 64] = sp[eb + tid - 64];

    const int lane = tid & 63;
    const int wv   = tid >> 6;
    const int mn   = lane & 15;
    const int q    = lane >> 4;
    const int srow = tid >> 2;          // staging row 0..63
    const int sseg = tid & 3;           // 8-elem segment
    const int bn   = tid >> 1;          // 0..127
    const int bk   = (tid & 1) << 4;    // 0 or 16

    __syncthreads();

    f32x4 acc[8];
#pragma unroll
    for (int t = 0; t < 8; ++t) acc[t] = (f32x4)0.0f;

    // prefetch registers
    float4 pa0, pa1;       // x-chunk staging (fp32)
    uint4  pae;            // ef-chunk staging (bf16)
    uint4  pb0, pb1;       // weight staging

    // ---- GEMM1: 12 k-steps of 32, register-prefetched ----
    {
        // load chunk 0
        const float* spx = x + (long)dv[srow] * HIDDEN + (sseg << 3);
        pa0 = *(const float4*)spx;
        pa1 = *(const float4*)(spx + 4);
        const unsigned short* wp = W1T + (long)bn * 384 + bk;
        pb0 = *(const uint4*)wp;
        pb1 = *(const uint4*)(wp + 8);
    }
    for (int c = 0; c < 12; ++c) {
        // store prefetched chunk c into LDS
        if (c < 8) {
            uint4 w;
            w.x = pack2(pa0.x, pa0.y); w.y = pack2(pa0.z, pa0.w);
            w.z = pack2(pa1.x, pa1.y); w.w = pack2(pa1.z, pa1.w);
            *(uint4*)&As[srow * 40 + (sseg << 3)] = w;
        } else {
            *(uint4*)&As[srow * 40 + (sseg << 3)] = pae;
        }
        *(uint4*)&Bs[bn * 40 + bk]     = pb0;
        *(uint4*)&Bs[bn * 40 + bk + 8] = pb1;
        __syncthreads();

        // issue loads for chunk c+1
        if (c + 1 < 12) {
            const int cn = c + 1;
            if (cn < 8) {
                const int* sI = (cn < 4) ? dv : sv;
                const float* spx = x + (long)sI[srow] * HIDDEN + ((cn & 3) << 5) + (sseg << 3);
                pa0 = *(const float4*)spx;
                pa1 = *(const float4*)(spx + 4);
            } else {
                pae = *(const uint4*)(ef + (eb + srow) * HIDDEN + ((cn - 8) << 5) + (sseg << 3));
            }
            const unsigned short* wp = W1T + (long)bn * 384 + (cn << 5) + bk;
            pb0 = *(const uint4*)wp;
            pb1 = *(const uint4*)(wp + 8);
        }

        short8 af = *(short8*)&As[(wv * 16 + mn) * 40 + (q << 3)];
#pragma unroll
        for (int nt = 0; nt < 8; ++nt) {
            short8 bf = *(short8*)&Bs[(nt * 16 + mn) * 40 + (q << 3)];
            acc[nt] = __builtin_amdgcn_mfma_f32_16x16x32_bf16(af, bf, acc[nt], 0, 0, 0);
        }
        __syncthreads();
    }

    // ---- H = relu(acc + b1) -> Hs bf16 (wave-private rows) ----
#pragma unroll
    for (int nt = 0; nt < 8; ++nt) {
        float b1v = b1[nt * 16 + mn];
#pragma unroll
        for (int r = 0; r < 4; ++r) {
            float hv = fmaxf(acc[nt][r] + b1v, 0.0f);
            Hs[(wv * 16 + q * 4 + r) * 136 + nt * 16 + mn] = f2bf(hv);
        }
    }

    // ---- GEMM2: 4 k-steps of 32, register-prefetched ----
    f32x4 acc2[8];
#pragma unroll
    for (int t = 0; t < 8; ++t) acc2[t] = (f32x4)0.0f;
    {
        const unsigned short* wp = W2T + (long)bn * 128 + bk;
        pb0 = *(const uint4*)wp;
        pb1 = *(const uint4*)(wp + 8);
    }
    for (int c = 0; c < 4; ++c) {
        *(uint4*)&Bs[bn * 40 + bk]     = pb0;
        *(uint4*)&Bs[bn * 40 + bk + 8] = pb1;
        __syncthreads();
        if (c + 1 < 4) {
            const unsigned short* wp = W2T + (long)bn * 128 + ((c + 1) << 5) + bk;
            pb0 = *(const uint4*)wp;
            pb1 = *(const uint4*)(wp + 8);
        }
        short8 af = *(short8*)&Hs[(wv * 16 + mn) * 136 + (c << 5) + (q << 3)];
#pragma unroll
        for (int nt = 0; nt < 8; ++nt) {
            short8 bf = *(short8*)&Bs[(nt * 16 + mn) * 40 + (q << 3)];
            acc2[nt] = __builtin_amdgcn_mfma_f32_16x16x32_bf16(af, bf, acc2[nt], 0, 0, 0);
        }
        __syncthreads();
    }

    // ---- m = acc2 + b2 -> Hs bf16 (wave-private rows) ----
#pragma unroll
    for (int nt = 0; nt < 8; ++nt) {
        float b2v = b2[nt * 16 + mn];
#pragma unroll
        for (int r = 0; r < 4; ++r) {
            Hs[(wv * 16 + q * 4 + r) * 136 + nt * 16 + mn] = f2bf(acc2[nt][r] + b2v);
        }
    }
    __syncthreads();

    // ---- ef += m (coalesced, full rows) ----
    {
        unsigned short* ep_ = ef + (eb + srow) * HIDDEN;
#pragma unroll
        for (int i = 0; i < 4; ++i) {
            int col = (sseg << 3) + (i << 5);
            uint4 mh = *(uint4*)&Hs[srow * 136 + col];
            uint4 eo = *(const uint4*)(ep_ + col);
            float m[8], e[8];
            unpack8(mh, m);
            unpack8(eo, e);
            uint4 nw;
            nw.x = pack2(e[0] + m[0], e[1] + m[1]);
            nw.y = pack2(e[2] + m[2], e[3] + m[3]);
            nw.z = pack2(e[4] + m[4], e[5] + m[5]);
            nw.w = pack2(e[6] + m[6], e[7] + m[7]);
            *(uint4*)(ep_ + col) = nw;
        }
    }

    // ---- segmented reduction by dst-run: one atomic row per run ----
    {
        const int colT = tid & 127;
        const int half = tid >> 7;          // 0: rows 0..31, 1: rows 32..63
        float s = 0.0f;
        int cur = dv[half * 32];
        for (int r = 0; r < 32; ++r) {
            const int row = half * 32 + r;
            const int d = dv[row];
            if (d != cur) {
                atomicAdd(&sums[(long)cur * HIDDEN + colT], s);
                s = 0.0f;
                cur = d;
            }
            s += bf2f(Hs[row * 136 + colT]);
        }
        atomicAdd(&sums[(long)cur * HIDDEN + colT], s);
    }
}

// ---------------------------------------------------------------------------
// MFMA node layer. 64 nodes x 128 out per block.
// ---------------------------------------------------------------------------
__global__ __launch_bounds__(256, 4)
void node_layer_mfma(float* __restrict__ x,
                     const float* __restrict__ sums,
                     const int* __restrict__ deg,
                     const unsigned short* __restrict__ N1T,  // [128][256] bf16
                     const float* __restrict__ b1,
                     const unsigned short* __restrict__ N2T,  // [128][128] bf16
                     const float* __restrict__ b2)
{
    __shared__ __align__(16) unsigned short As[64 * 40];
    __shared__ __align__(16) unsigned short Bs[128 * 40];
    __shared__ __align__(16) unsigned short Hs[64 * 136];
    __shared__ float cInv[64];

    const int tid = threadIdx.x;
    const long n0 = (long)blockIdx.x * 64;
    if (tid < 64) {
        long n = n0 + tid;
        cInv[tid] = (n < NNODES) ? 1.0f / fmaxf((float)deg[n], 1.0f) : 0.0f;
    }

    const int lane = tid & 63;
    const int wv   = tid >> 6;
    const int mn   = lane & 15;
    const int q    = lane >> 4;
    const int srow = tid >> 2;
    const int sseg = tid & 3;
    const int bn   = tid >> 1;
    const int bk   = (tid & 1) << 4;

    long nr = n0 + srow;
    if (nr >= NNODES) nr = NNODES - 1;

    __syncthreads();

    f32x4 acc[8];
#pragma unroll
    for (int t = 0; t < 8; ++t) acc[t] = (f32x4)0.0f;

    float4 pa0, pa1;
    uint4 pb0, pb1;
    {
        const float* spx = x + nr * HIDDEN + (sseg << 3);
        pa0 = *(const float4*)spx;
        pa1 = *(const float4*)(spx + 4);
        const unsigned short* wp = N1T + (long)bn * 256 + bk;
        pb0 = *(const uint4*)wp;
        pb1 = *(const uint4*)(wp + 8);
    }
    float scCur = 1.0f;
    for (int c = 0; c < 8; ++c) {
        {
            uint4 w;
            w.x = pack2(pa0.x * scCur, pa0.y * scCur); w.y = pack2(pa0.z * scCur, pa0.w * scCur);
            w.z = pack2(pa1.x * scCur, pa1.y * scCur); w.w = pack2(pa1.z * scCur, pa1.w * scCur);
            *(uint4*)&As[srow * 40 + (sseg << 3)] = w;
        }
        *(uint4*)&Bs[bn * 40 + bk]     = pb0;
        *(uint4*)&Bs[bn * 40 + bk + 8] = pb1;
        __syncthreads();
        if (c + 1 < 8) {
            const int cn = c + 1;
            const float* base = (cn < 4) ? x : sums;
            scCur = (cn < 4) ? 1.0f : cInv[srow];
            const float* spx = base + nr * HIDDEN + ((cn & 3) << 5) + (sseg << 3);
            pa0 = *(const float4*)spx;
            pa1 = *(const float4*)(spx + 4);
            const unsigned short* wp = N1T + (long)bn * 256 + (cn << 5) + bk;
            pb0 = *(const uint4*)wp;
            pb1 = *(const uint4*)(wp + 8);
        }
        short8 af = *(short8*)&As[(wv * 16 + mn) * 40 + (q << 3)];
#pragma unroll
        for (int nt = 0; nt < 8; ++nt) {
            short8 bf = *(short8*)&Bs[(nt * 16 + mn) * 40 + (q << 3)];
            acc[nt] = __builtin_amdgcn_mfma_f32_16x16x32_bf16(af, bf, acc[nt], 0, 0, 0);
        }
        __syncthreads();
    }

#pragma unroll
    for (int nt = 0; nt < 8; ++nt) {
        float b1v = b1[nt * 16 + mn];
#pragma unroll
        for (int r = 0; r < 4; ++r) {
            float hv = fmaxf(acc[nt][r] + b1v, 0.0f);
            Hs[(wv * 16 + q * 4 + r) * 136 + nt * 16 + mn] = f2bf(hv);
        }
    }

    f32x4 acc2[8];
#pragma unroll
    for (int t = 0; t < 8; ++t) acc2[t] = (f32x4)0.0f;
    {
        const unsigned short* wp = N2T + (long)bn * 128 + bk;
        pb0 = *(const uint4*)wp;
        pb1 = *(const uint4*)(wp + 8);
    }
    for (int c = 0; c < 4; ++c) {
        *(uint4*)&Bs[bn * 40 + bk]     = pb0;
        *(uint4*)&Bs[bn * 40 + bk + 8] = pb1;
        __syncthreads();
        if (c + 1 < 4) {
            const unsigned short* wp = N2T + (long)bn * 128 + ((c + 1) << 5) + bk;
            pb0 = *(const uint4*)wp;
            pb1 = *(const uint4*)(wp + 8);
        }
        short8 af = *(short8*)&Hs[(wv * 16 + mn) * 136 + (c << 5) + (q << 3)];
#pragma unroll
        for (int nt = 0; nt < 8; ++nt) {
            short8 bf = *(short8*)&Bs[(nt * 16 + mn) * 40 + (q << 3)];
            acc2[nt] = __builtin_amdgcn_mfma_f32_16x16x32_bf16(af, bf, acc2[nt], 0, 0, 0);
        }
        __syncthreads();
    }

    // ---- x += acc2 + b2 (exact fp32 residual) ----
#pragma unroll
    for (int nt = 0; nt < 8; ++nt) {
        float b2v = b2[nt * 16 + mn];
#pragma unroll
        for (int r = 0; r < 4; ++r) {
            long row = n0 + wv * 16 + q * 4 + r;
            if (row < NNODES) {
                float* p = x + row * HIDDEN + nt * 16 + mn;
                *p += acc2[nt][r] + b2v;
            }
        }
    }
}

// ---------------------------------------------------------------------------
// Decoder + row L2-normalize (one wave per node)
// ---------------------------------------------------------------------------
__global__ void decode_kernel(const float* __restrict__ x,
                              const float* __restrict__ w,
                              const float* __restrict__ b,
                              float* __restrict__ out)
{
    int gid = blockIdx.x * blockDim.x + threadIdx.x;
    int node = gid >> 6;
    int lane = threadIdx.x & 63;
    if (node >= NNODES) return;
    float a0 = 0.f, a1 = 0.f, a2 = 0.f;
#pragma unroll
    for (int k = lane; k < HIDDEN; k += 64) {
        float xv = x[(long)node * HIDDEN + k];
        a0 = fmaf(xv, w[k * 3 + 0], a0);
        a1 = fmaf(xv, w[k * 3 + 1], a1);
        a2 = fmaf(xv, w[k * 3 + 2], a2);
    }
#pragma unroll
    for (int off = 32; off > 0; off >>= 1) {
        a0 += __shfl_down(a0, off);
        a1 += __shfl_down(a1, off);
        a2 += __shfl_down(a2, off);
    }
    if (lane == 0) {
        a0 += b[0]; a1 += b[1]; a2 += b[2];
        float nrm = sqrtf(a0 * a0 + a1 * a1 + a2 * a2);
        float inv = 1.0f / fmaxf(nrm, 1e-12f);
        out[(long)node * 3 + 0] = a0 * inv;
        out[(long)node * 3 + 1] = a1 * inv;
        out[(long)node * 3 + 2] = a2 * inv;
    }
}

// ---------------------------------------------------------------------------
extern "C" void kernel_launch(void* const* d_in, const int* in_sizes, int n_in,
                              void* d_out, int out_size, void* d_ws, size_t ws_size,
                              hipStream_t stream)
{
    const float* edge_attr = (const float*)d_in[1];
    const int*   ei        = (const int*)d_in[2];
    const float* enc_w     = (const float*)d_in[3];
    const float* enc_b     = (const float*)d_in[4];
    const float* dec_w     = (const float*)d_in[5];
    const float* dec_b     = (const float*)d_in[6];
    const float* edge_w1   = (const float*)d_in[7];
    const float* edge_b1   = (const float*)d_in[8];
    const float* edge_w2   = (const float*)d_in[9];
    const float* edge_b2   = (const float*)d_in[10];
    const float* node_w1   = (const float*)d_in[11];
    const float* node_b1   = (const float*)d_in[12];
    const float* node_w2   = (const float*)d_in[13];
    const float* node_b2   = (const float*)d_in[14];

    // workspace layout (bytes), 16B-aligned, total ~229.8 MB
    char* ws = (char*)d_ws;
    unsigned short* ef  = (unsigned short*)(ws);                  // 163,840,000
    float* x      = (float*)(ws + 163840000L);                    //  25,600,000
    float* sums   = (float*)(ws + 189440000L);                    //  25,600,000
    int*   src32  = (int*)  (ws + 215040000L);                    //   2,560,000
    int*   dst32  = (int*)  (ws + 217600000L);                    //   2,560,000
    int*   sp     = (int*)  (ws + 220160000L);                    //   2,560,000
    int*   dp     = (int*)  (ws + 222720000L);                    //   2,560,000
    int*   eperm  = (int*)  (ws + 225280000L);                    //   2,560,000
    int*   deg    = (int*)  (ws + 227840000L);                    //     200,704
    int*   off    = (int*)  (ws + 228040704L);                    //     200,704
    int*   cursor = (int*)  (ws + 228241408L);                    //     200,704
    int*   flag   = (int*)  (ws + 228442112L);                    //          64
    unsigned short* W1T = (unsigned short*)(ws + 228442176L);     //     589,824
    unsigned short* W2T = (unsigned short*)(ws + 229032000L);     //     196,608
    unsigned short* N1T = (unsigned short*)(ws + 229228608L);     //     393,216
    unsigned short* N2T = (unsigned short*)(ws + 229621824L);     //     196,608

    float* out = (float*)d_out;

    hipMemsetAsync(x, 0, (size_t)NNODES * HIDDEN * sizeof(float), stream);
    hipMemsetAsync(deg, 0, 200704, stream);

    detect_kernel<<<1, 64, 0, stream>>>(ei, flag);
    normidx_kernel<<<(NEDGES + 255) / 256, 256, 0, stream>>>(ei, flag, src32, dst32);
    degree_kernel<<<(NEDGES + 255) / 256, 256, 0, stream>>>(dst32, deg);
    scan_kernel<<<1, SCAN_T, 0, stream>>>(deg, off, cursor);
    scatter_kernel<<<(NEDGES + 255) / 256, 256, 0, stream>>>(src32, dst32, cursor, sp, dp, eperm);
    encode_kernel<<<(NEDGES * 32 + 255) / 256, 256, 0, stream>>>(edge_attr, enc_w, enc_b, eperm, ef);

    transpose_kernel<<<(6 * 384 * 128 + 255) / 256, 256, 0, stream>>>(edge_w1, W1T, 384, 128, 6);
    transpose_kernel<<<(6 * 128 * 128 + 255) / 256, 256, 0, stream>>>(edge_w2, W2T, 128, 128, 6);
    transpose_kernel<<<(6 * 256 * 128 + 255) / 256, 256, 0, stream>>>(node_w1, N1T, 256, 128, 6);
    transpose_kernel<<<(6 * 128 * 128 + 255) / 256, 256, 0, stream>>>(node_w2, N2T, 128, 128, 6);

    for (int l = 0; l < NLAYERS; ++l) {
        hipMemsetAsync(sums, 0, (size_t)NNODES * HIDDEN * sizeof(float), stream);
        edge_layer_mfma<<<NEDGES / 64, 256, 0, stream>>>(
            x, ef, sums, sp, dp,
            W1T + (long)l * 384 * 128, edge_b1 + (long)l * HIDDEN,
            W2T + (long)l * 128 * 128, edge_b2 + (long)l * HIDDEN);
        node_layer_mfma<<<(NNODES + 63) / 64, 256, 0, stream>>>(
            x, sums, deg,
            N1T + (long)l * 256 * 128, node_b1 + (long)l * HIDDEN,
            N2T + (long)l * 128 * 128, node_b2 + (long)l * HIDDEN);
    }

    decode_kernel<<<(NNODES * 64 + 255) / 256, 256, 0, stream>>>(x, dec_w, dec_b, out);
}

// Round 5
// 1814.998 us; speedup vs baseline: 7.6687x; 1.0060x over previous
//
#include <hip/hip_runtime.h>
#include <cstdint>

#define HIDDEN  128
#define NLAYERS 6
#define NNODES  50000
#define NEDGES  640000

typedef short short8 __attribute__((ext_vector_type(8)));
typedef float f32x4  __attribute__((ext_vector_type(4)));

// ---- bf16 <-> f32 helpers (RNE) -------------------------------------------
__device__ __forceinline__ float bf2f(unsigned short u) {
    return __uint_as_float(((unsigned int)u) << 16);
}
__device__ __forceinline__ unsigned short f2bf(float f) {
    unsigned int u = __float_as_uint(f);
    unsigned int r = u + 0x7FFFu + ((u >> 16) & 1u);
    return (unsigned short)(r >> 16);
}
__device__ __forceinline__ unsigned int pack2(float a, float b) {
    return (unsigned int)f2bf(a) | ((unsigned int)f2bf(b) << 16);
}
__device__ __forceinline__ void unpack8(uint4 v, float* f) {
    f[0] = bf2f((unsigned short)(v.x & 0xffff)); f[1] = bf2f((unsigned short)(v.x >> 16));
    f[2] = bf2f((unsigned short)(v.y & 0xffff)); f[3] = bf2f((unsigned short)(v.y >> 16));
    f[4] = bf2f((unsigned short)(v.z & 0xffff)); f[5] = bf2f((unsigned short)(v.z >> 16));
    f[6] = bf2f((unsigned short)(v.w & 0xffff)); f[7] = bf2f((unsigned short)(v.w >> 16));
}

// ---------------------------------------------------------------------------
// Index dtype detection + canonicalization
// ---------------------------------------------------------------------------
__global__ void detect_kernel(const int* __restrict__ ei, int* __restrict__ flag)
{
    int lane = threadIdx.x;
    int v = ei[2 * lane + 1];
    unsigned long long b = __ballot(v != 0);
    if (lane == 0) *flag = (b != 0ULL) ? 1 : 0;
}

__global__ void normidx_kernel(const int* __restrict__ ei, const int* __restrict__ flag,
                               int* __restrict__ s32, int* __restrict__ d32)
{
    int e = blockIdx.x * blockDim.x + threadIdx.x;
    if (e >= NEDGES) return;
    int s, d;
    if (*flag) { s = ei[e]; d = ei[NEDGES + e]; }
    else       { s = ei[2 * e]; d = ei[2 * (NEDGES + e)]; }
    s32[e] = min(max(s, 0), NNODES - 1);
    d32[e] = min(max(d, 0), NNODES - 1);
}

__global__ void degree_kernel(const int* __restrict__ dst, int* __restrict__ deg)
{
    int e = blockIdx.x * blockDim.x + threadIdx.x;
    if (e < NEDGES) atomicAdd(&deg[dst[e]], 1);
}

// ---------------------------------------------------------------------------
// Exclusive scan over deg[0..NNODES) -> off, cursor. One 1024-thread block.
// ---------------------------------------------------------------------------
#define SCAN_T 1024
__global__ void scan_kernel(const int* __restrict__ deg, int* __restrict__ off,
                            int* __restrict__ cursor)
{
    __shared__ int part[SCAN_T];
    const int t = threadIdx.x;
    const int CH = (NNODES + SCAN_T - 1) / SCAN_T;
    const int base = t * CH;
    int s = 0;
    for (int i = 0; i < CH; ++i) {
        int idx = base + i;
        if (idx < NNODES) s += deg[idx];
    }
    part[t] = s;
    __syncthreads();
    for (int d = 1; d < SCAN_T; d <<= 1) {
        int v = (t >= d) ? part[t - d] : 0;
        __syncthreads();
        part[t] += v;
        __syncthreads();
    }
    int run = (t == 0) ? 0 : part[t - 1];
    for (int i = 0; i < CH; ++i) {
        int idx = base + i;
        if (idx < NNODES) {
            off[idx] = run;
            cursor[idx] = run;
            run += deg[idx];
        }
    }
    if (t == SCAN_T - 1) off[NNODES] = run;
}

__global__ void scatter_kernel(const int* __restrict__ s32, const int* __restrict__ d32,
                               int* __restrict__ cursor,
                               int* __restrict__ sp, int* __restrict__ dp, int* __restrict__ ep)
{
    int e = blockIdx.x * blockDim.x + threadIdx.x;
    if (e >= NEDGES) return;
    int d = d32[e];
    int p = atomicAdd(&cursor[d], 1);
    sp[p] = s32[e];
    dp[p] = d;
    ep[p] = e;
}

// ---------------------------------------------------------------------------
// Weight transpose+convert: W [L][K][N] fp32 -> WT [L][N][K] bf16
// ---------------------------------------------------------------------------
__global__ void transpose_kernel(const float* __restrict__ W, unsigned short* __restrict__ WT,
                                 int K, int N, int L)
{
    long idx = (long)blockIdx.x * 256 + threadIdx.x;
    long tot = (long)L * K * N;
    if (idx >= tot) return;
    int kn = (int)(idx % ((long)K * N));
    int l  = (int)(idx / ((long)K * N));
    int k = kn / N;
    int n = kn % N;
    WT[(long)l * K * N + (long)n * K + k] = f2bf(W[idx]);
}

// ---------------------------------------------------------------------------
// Encoder into permuted layout: ef[p] = enc(ea[ep[p]])
// ---------------------------------------------------------------------------
__global__ void encode_kernel(const float* __restrict__ ea,
                              const float* __restrict__ w,
                              const float* __restrict__ b,
                              const int* __restrict__ ep,
                              unsigned short* __restrict__ ef)
{
    int idx = blockIdx.x * blockDim.x + threadIdx.x;
    int p = idx >> 5;
    if (p >= NEDGES) return;
    int e = ep[p];
    int j = (idx & 31) << 2;
    float a0 = ea[e * 3 + 0], a1 = ea[e * 3 + 1], a2 = ea[e * 3 + 2];
    float4 w0 = *(const float4*)(w + 0 * HIDDEN + j);
    float4 w1 = *(const float4*)(w + 1 * HIDDEN + j);
    float4 w2 = *(const float4*)(w + 2 * HIDDEN + j);
    float4 bb = *(const float4*)(b + j);
    ushort4 o;
    o.x = f2bf(fmaf(a0, w0.x, fmaf(a1, w1.x, fmaf(a2, w2.x, bb.x))));
    o.y = f2bf(fmaf(a0, w0.y, fmaf(a1, w1.y, fmaf(a2, w2.y, bb.y))));
    o.z = f2bf(fmaf(a0, w0.z, fmaf(a1, w1.z, fmaf(a2, w2.z, bb.z))));
    o.w = f2bf(fmaf(a0, w0.w, fmaf(a1, w1.w, fmaf(a2, w2.w, bb.w))));
    *(ushort4*)(ef + (long)p * HIDDEN + j) = o;
}

// ---------------------------------------------------------------------------
// MFMA edge layer on dst-sorted edges. 128 edges x 128 out per block, 4 waves,
// each wave owns 32 rows (2 A-frags x 8 B-frags = 16 MFMA per k-step).
// LDS: Hs[128x136] aliases As[128x40] (As dead before Hs written).
// ---------------------------------------------------------------------------
__global__ __launch_bounds__(256, 3)
void edge_layer_mfma(const float* __restrict__ x,
                     unsigned short* __restrict__ ef,
                     float* __restrict__ sums,
                     const int* __restrict__ sp,
                     const int* __restrict__ dp,
                     const unsigned short* __restrict__ W1T,  // [128][384] bf16
                     const float* __restrict__ b1,
                     const unsigned short* __restrict__ W2T,  // [128][128] bf16
                     const float* __restrict__ b2)
{
    // 0      .. 34816 : Hs (stride 136) / As (stride 40) aliased
    // 34816  .. 45056 : Bs (stride 40)
    __shared__ __align__(16) unsigned char buf[45056];
    unsigned short* As = (unsigned short*)buf;
    unsigned short* Hs = (unsigned short*)buf;
    unsigned short* Bs = (unsigned short*)(buf + 34816);
    __shared__ int dv[128];
    __shared__ int sv[128];

    const int tid = threadIdx.x;
    const long eb = (long)blockIdx.x * 128;
    if (tid < 128) dv[tid]       = dp[eb + tid];
    else           sv[tid - 128] = sp[eb + tid - 128];

    const int lane = tid & 63;
    const int wv   = tid >> 6;
    const int mn   = lane & 15;
    const int q    = lane >> 4;
    const int srow = tid >> 2;          // staging row 0..63 (and +64)
    const int sseg = tid & 3;           // 8-elem k-segment
    const int bn   = tid >> 1;          // 0..127
    const int bk   = (tid & 1) << 4;    // 0 or 16

    __syncthreads();

    f32x4 acc[2][8];
#pragma unroll
    for (int h = 0; h < 2; ++h)
#pragma unroll
        for (int t = 0; t < 8; ++t) acc[h][t] = (f32x4)0.0f;

    // prefetch registers
    float4 pxa0, pxa1, pxb0, pxb1;   // x rows srow / srow+64 (fp32)
    uint4  pea, peb;                 // ef rows (bf16)
    uint4  pw0, pw1;                 // weights

    {   // chunk 0 loads
        const float* spa = x + (long)dv[srow] * HIDDEN + (sseg << 3);
        const float* spb = x + (long)dv[srow + 64] * HIDDEN + (sseg << 3);
        pxa0 = *(const float4*)spa; pxa1 = *(const float4*)(spa + 4);
        pxb0 = *(const float4*)spb; pxb1 = *(const float4*)(spb + 4);
        const unsigned short* wp = W1T + (long)bn * 384 + bk;
        pw0 = *(const uint4*)wp;
        pw1 = *(const uint4*)(wp + 8);
    }

    // ---- GEMM1: 12 k-steps of 32 ----
    for (int c = 0; c < 12; ++c) {
        if (c < 8) {
            uint4 w;
            w.x = pack2(pxa0.x, pxa0.y); w.y = pack2(pxa0.z, pxa0.w);
            w.z = pack2(pxa1.x, pxa1.y); w.w = pack2(pxa1.z, pxa1.w);
            *(uint4*)&As[srow * 40 + (sseg << 3)] = w;
            w.x = pack2(pxb0.x, pxb0.y); w.y = pack2(pxb0.z, pxb0.w);
            w.z = pack2(pxb1.x, pxb1.y); w.w = pack2(pxb1.z, pxb1.w);
            *(uint4*)&As[(srow + 64) * 40 + (sseg << 3)] = w;
        } else {
            *(uint4*)&As[srow * 40 + (sseg << 3)]        = pea;
            *(uint4*)&As[(srow + 64) * 40 + (sseg << 3)] = peb;
        }
        *(uint4*)&Bs[bn * 40 + bk]     = pw0;
        *(uint4*)&Bs[bn * 40 + bk + 8] = pw1;
        __syncthreads();

        if (c + 1 < 12) {
            const int cn = c + 1;
            if (cn < 8) {
                const int* sI = (cn < 4) ? dv : sv;
                const int ko = ((cn & 3) << 5) + (sseg << 3);
                const float* spa = x + (long)sI[srow] * HIDDEN + ko;
                const float* spb = x + (long)sI[srow + 64] * HIDDEN + ko;
                pxa0 = *(const float4*)spa; pxa1 = *(const float4*)(spa + 4);
                pxb0 = *(const float4*)spb; pxb1 = *(const float4*)(spb + 4);
            } else {
                const int ko = ((cn - 8) << 5) + (sseg << 3);
                pea = *(const uint4*)(ef + (eb + srow) * HIDDEN + ko);
                peb = *(const uint4*)(ef + (eb + srow + 64) * HIDDEN + ko);
            }
            const unsigned short* wp = W1T + (long)bn * 384 + (cn << 5) + bk;
            pw0 = *(const uint4*)wp;
            pw1 = *(const uint4*)(wp + 8);
        }

        short8 af0 = *(short8*)&As[(wv * 32 + mn) * 40 + (q << 3)];
        short8 af1 = *(short8*)&As[(wv * 32 + 16 + mn) * 40 + (q << 3)];
#pragma unroll
        for (int nt = 0; nt < 8; ++nt) {
            short8 bf = *(short8*)&Bs[(nt * 16 + mn) * 40 + (q << 3)];
            acc[0][nt] = __builtin_amdgcn_mfma_f32_16x16x32_bf16(af0, bf, acc[0][nt], 0, 0, 0);
            acc[1][nt] = __builtin_amdgcn_mfma_f32_16x16x32_bf16(af1, bf, acc[1][nt], 0, 0, 0);
        }
        __syncthreads();
    }

    // ---- H = relu(acc + b1) -> Hs bf16 (wave-private rows; As now dead) ----
#pragma unroll
    for (int h = 0; h < 2; ++h)
#pragma unroll
        for (int nt = 0; nt < 8; ++nt) {
            float b1v = b1[nt * 16 + mn];
#pragma unroll
            for (int r = 0; r < 4; ++r) {
                float hv = fmaxf(acc[h][nt][r] + b1v, 0.0f);
                Hs[(wv * 32 + h * 16 + q * 4 + r) * 136 + nt * 16 + mn] = f2bf(hv);
            }
        }

    // ---- GEMM2: 4 k-steps of 32 ----
    f32x4 acc2[2][8];
#pragma unroll
    for (int h = 0; h < 2; ++h)
#pragma unroll
        for (int t = 0; t < 8; ++t) acc2[h][t] = (f32x4)0.0f;
    {
        const unsigned short* wp = W2T + (long)bn * 128 + bk;
        pw0 = *(const uint4*)wp;
        pw1 = *(const uint4*)(wp + 8);
    }
    for (int c = 0; c < 4; ++c) {
        *(uint4*)&Bs[bn * 40 + bk]     = pw0;
        *(uint4*)&Bs[bn * 40 + bk + 8] = pw1;
        __syncthreads();
        if (c + 1 < 4) {
            const unsigned short* wp = W2T + (long)bn * 128 + ((c + 1) << 5) + bk;
            pw0 = *(const uint4*)wp;
            pw1 = *(const uint4*)(wp + 8);
        }
        short8 af0 = *(short8*)&Hs[(wv * 32 + mn) * 136 + (c << 5) + (q << 3)];
        short8 af1 = *(short8*)&Hs[(wv * 32 + 16 + mn) * 136 + (c << 5) + (q << 3)];
#pragma unroll
        for (int nt = 0; nt < 8; ++nt) {
            short8 bf = *(short8*)&Bs[(nt * 16 + mn) * 40 + (q << 3)];
            acc2[0][nt] = __builtin_amdgcn_mfma_f32_16x16x32_bf16(af0, bf, acc2[0][nt], 0, 0, 0);
            acc2[1][nt] = __builtin_amdgcn_mfma_f32_16x16x32_bf16(af1, bf, acc2[1][nt], 0, 0, 0);
        }
        __syncthreads();
    }

    // ---- m = acc2 + b2 -> Hs bf16 (wave-private rows) ----
#pragma unroll
    for (int h = 0; h < 2; ++h)
#pragma unroll
        for (int nt = 0; nt < 8; ++nt) {
            float b2v = b2[nt * 16 + mn];
#pragma unroll
            for (int r = 0; r < 4; ++r) {
                Hs[(wv * 32 + h * 16 + q * 4 + r) * 136 + nt * 16 + mn] = f2bf(acc2[h][nt][r] + b2v);
            }
        }
    __syncthreads();

    // ---- ef += m (coalesced, full rows) ----
    {
        const int row = tid >> 1;
        const int ch  = (tid & 1) << 6;       // column half: 0 or 64
        unsigned short* ep_ = ef + (eb + row) * HIDDEN + ch;
        const unsigned short* hp = &Hs[row * 136 + ch];
#pragma unroll
        for (int i = 0; i < 8; ++i) {
            uint4 mh = *(uint4*)(hp + (i << 3));
            uint4 eo = *(const uint4*)(ep_ + (i << 3));
            float m[8], e[8];
            unpack8(mh, m);
            unpack8(eo, e);
            uint4 nw;
            nw.x = pack2(e[0] + m[0], e[1] + m[1]);
            nw.y = pack2(e[2] + m[2], e[3] + m[3]);
            nw.z = pack2(e[4] + m[4], e[5] + m[5]);
            nw.w = pack2(e[6] + m[6], e[7] + m[7]);
            *(uint4*)(ep_ + (i << 3)) = nw;
        }
    }

    // ---- segmented reduction by dst-run: one atomic row per run ----
    {
        const int cp = (tid & 63) << 1;       // column pair
        const int qr = tid >> 6;              // row quarter 0..3
        float s0 = 0.0f, s1 = 0.0f;
        int cur = dv[qr * 32];
        for (int r = 0; r < 32; ++r) {
            const int row = qr * 32 + r;
            const int d = dv[row];
            if (d != cur) {
                atomicAdd(&sums[(long)cur * HIDDEN + cp], s0);
                atomicAdd(&sums[(long)cur * HIDDEN + cp + 1], s1);
                s0 = 0.0f; s1 = 0.0f;
                cur = d;
            }
            unsigned int u = *(unsigned int*)&Hs[row * 136 + cp];
            s0 += bf2f((unsigned short)(u & 0xffff));
            s1 += bf2f((unsigned short)(u >> 16));
        }
        atomicAdd(&sums[(long)cur * HIDDEN + cp], s0);
        atomicAdd(&sums[(long)cur * HIDDEN + cp + 1], s1);
    }
}

// ---------------------------------------------------------------------------
// MFMA node layer. 64 nodes x 128 out per block. Zeros its sums rows after
// consuming them (replaces per-layer memset).
// ---------------------------------------------------------------------------
__global__ __launch_bounds__(256, 4)
void node_layer_mfma(float* __restrict__ x,
                     float* __restrict__ sums,
                     const int* __restrict__ deg,
                     const unsigned short* __restrict__ N1T,  // [128][256] bf16
                     const float* __restrict__ b1,
                     const unsigned short* __restrict__ N2T,  // [128][128] bf16
                     const float* __restrict__ b2)
{
    __shared__ __align__(16) unsigned short As[64 * 40];
    __shared__ __align__(16) unsigned short Bs[128 * 40];
    __shared__ __align__(16) unsigned short Hs[64 * 136];
    __shared__ float cInv[64];

    const int tid = threadIdx.x;
    const long n0 = (long)blockIdx.x * 64;
    if (tid < 64) {
        long n = n0 + tid;
        cInv[tid] = (n < NNODES) ? 1.0f / fmaxf((float)deg[n], 1.0f) : 0.0f;
    }

    const int lane = tid & 63;
    const int wv   = tid >> 6;
    const int mn   = lane & 15;
    const int q    = lane >> 4;
    const int srow = tid >> 2;
    const int sseg = tid & 3;
    const int bn   = tid >> 1;
    const int bk   = (tid & 1) << 4;

    long nr = n0 + srow;
    if (nr >= NNODES) nr = NNODES - 1;

    __syncthreads();

    f32x4 acc[8];
#pragma unroll
    for (int t = 0; t < 8; ++t) acc[t] = (f32x4)0.0f;

    float4 pa0, pa1;
    uint4 pb0, pb1;
    {
        const float* spx = x + nr * HIDDEN + (sseg << 3);
        pa0 = *(const float4*)spx;
        pa1 = *(const float4*)(spx + 4);
        const unsigned short* wp = N1T + (long)bn * 256 + bk;
        pb0 = *(const uint4*)wp;
        pb1 = *(const uint4*)(wp + 8);
    }
    float scCur = 1.0f;
    for (int c = 0; c < 8; ++c) {
        {
            uint4 w;
            w.x = pack2(pa0.x * scCur, pa0.y * scCur); w.y = pack2(pa0.z * scCur, pa0.w * scCur);
            w.z = pack2(pa1.x * scCur, pa1.y * scCur); w.w = pack2(pa1.z * scCur, pa1.w * scCur);
            *(uint4*)&As[srow * 40 + (sseg << 3)] = w;
        }
        *(uint4*)&Bs[bn * 40 + bk]     = pb0;
        *(uint4*)&Bs[bn * 40 + bk + 8] = pb1;
        __syncthreads();
        if (c + 1 < 8) {
            const int cn = c + 1;
            const float* base = (cn < 4) ? x : sums;
            scCur = (cn < 4) ? 1.0f : cInv[srow];
            const float* spx = base + nr * HIDDEN + ((cn & 3) << 5) + (sseg << 3);
            pa0 = *(const float4*)spx;
            pa1 = *(const float4*)(spx + 4);
            const unsigned short* wp = N1T + (long)bn * 256 + (cn << 5) + bk;
            pb0 = *(const uint4*)wp;
            pb1 = *(const uint4*)(wp + 8);
        }
        short8 af = *(short8*)&As[(wv * 16 + mn) * 40 + (q << 3)];
#pragma unroll
        for (int nt = 0; nt < 8; ++nt) {
            short8 bf = *(short8*)&Bs[(nt * 16 + mn) * 40 + (q << 3)];
            acc[nt] = __builtin_amdgcn_mfma_f32_16x16x32_bf16(af, bf, acc[nt], 0, 0, 0);
        }
        __syncthreads();
    }

    // zero own sums rows for the next layer (sums fully consumed above)
    {
        long row = n0 + srow;
        if (row < NNODES) {
            float4 z = make_float4(0.f, 0.f, 0.f, 0.f);
            float* p = sums + row * HIDDEN + (sseg << 5);
#pragma unroll
            for (int i = 0; i < 8; ++i) ((float4*)p)[i] = z;
        }
    }

#pragma unroll
    for (int nt = 0; nt < 8; ++nt) {
        float b1v = b1[nt * 16 + mn];
#pragma unroll
        for (int r = 0; r < 4; ++r) {
            float hv = fmaxf(acc[nt][r] + b1v, 0.0f);
            Hs[(wv * 16 + q * 4 + r) * 136 + nt * 16 + mn] = f2bf(hv);
        }
    }

    f32x4 acc2[8];
#pragma unroll
    for (int t = 0; t < 8; ++t) acc2[t] = (f32x4)0.0f;
    {
        const unsigned short* wp = N2T + (long)bn * 128 + bk;
        pb0 = *(const uint4*)wp;
        pb1 = *(const uint4*)(wp + 8);
    }
    for (int c = 0; c < 4; ++c) {
        *(uint4*)&Bs[bn * 40 + bk]     = pb0;
        *(uint4*)&Bs[bn * 40 + bk + 8] = pb1;
        __syncthreads();
        if (c + 1 < 4) {
            const unsigned short* wp = N2T + (long)bn * 128 + ((c + 1) << 5) + bk;
            pb0 = *(const uint4*)wp;
            pb1 = *(const uint4*)(wp + 8);
        }
        short8 af = *(short8*)&Hs[(wv * 16 + mn) * 136 + (c << 5) + (q << 3)];
#pragma unroll
        for (int nt = 0; nt < 8; ++nt) {
            short8 bf = *(short8*)&Bs[(nt * 16 + mn) * 40 + (q << 3)];
            acc2[nt] = __builtin_amdgcn_mfma_f32_16x16x32_bf16(af, bf, acc2[nt], 0, 0, 0);
        }
        __syncthreads();
    }

    // ---- x += acc2 + b2 (exact fp32 residual) ----
#pragma unroll
    for (int nt = 0; nt < 8; ++nt) {
        float b2v = b2[nt * 16 + mn];
#pragma unroll
        for (int r = 0; r < 4; ++r) {
            long row = n0 + wv * 16 + q * 4 + r;
            if (row < NNODES) {
                float* p = x + row * HIDDEN + nt * 16 + mn;
                *p += acc2[nt][r] + b2v;
            }
        }
    }
}

// ---------------------------------------------------------------------------
// Decoder + row L2-normalize (one wave per node)
// ---------------------------------------------------------------------------
__global__ void decode_kernel(const float* __restrict__ x,
                              const float* __restrict__ w,
                              const float* __restrict__ b,
                              float* __restrict__ out)
{
    int gid = blockIdx.x * blockDim.x + threadIdx.x;
    int node = gid >> 6;
    int lane = threadIdx.x & 63;
    if (node >= NNODES) return;
    float a0 = 0.f, a1 = 0.f, a2 = 0.f;
#pragma unroll
    for (int k = lane; k < HIDDEN; k += 64) {
        float xv = x[(long)node * HIDDEN + k];
        a0 = fmaf(xv, w[k * 3 + 0], a0);
        a1 = fmaf(xv, w[k * 3 + 1], a1);
        a2 = fmaf(xv, w[k * 3 + 2], a2);
    }
#pragma unroll
    for (int off = 32; off > 0; off >>= 1) {
        a0 += __shfl_down(a0, off);
        a1 += __shfl_down(a1, off);
        a2 += __shfl_down(a2, off);
    }
    if (lane == 0) {
        a0 += b[0]; a1 += b[1]; a2 += b[2];
        float nrm = sqrtf(a0 * a0 + a1 * a1 + a2 * a2);
        float inv = 1.0f / fmaxf(nrm, 1e-12f);
        out[(long)node * 3 + 0] = a0 * inv;
        out[(long)node * 3 + 1] = a1 * inv;
        out[(long)node * 3 + 2] = a2 * inv;
    }
}

// ---------------------------------------------------------------------------
extern "C" void kernel_launch(void* const* d_in, const int* in_sizes, int n_in,
                              void* d_out, int out_size, void* d_ws, size_t ws_size,
                              hipStream_t stream)
{
    const float* edge_attr = (const float*)d_in[1];
    const int*   ei        = (const int*)d_in[2];
    const float* enc_w     = (const float*)d_in[3];
    const float* enc_b     = (const float*)d_in[4];
    const float* dec_w     = (const float*)d_in[5];
    const float* dec_b     = (const float*)d_in[6];
    const float* edge_w1   = (const float*)d_in[7];
    const float* edge_b1   = (const float*)d_in[8];
    const float* edge_w2   = (const float*)d_in[9];
    const float* edge_b2   = (const float*)d_in[10];
    const float* node_w1   = (const float*)d_in[11];
    const float* node_b1   = (const float*)d_in[12];
    const float* node_w2   = (const float*)d_in[13];
    const float* node_b2   = (const float*)d_in[14];

    // workspace layout (bytes), 16B-aligned, total ~229.8 MB
    char* ws = (char*)d_ws;
    unsigned short* ef  = (unsigned short*)(ws);                  // 163,840,000
    float* x      = (float*)(ws + 163840000L);                    //  25,600,000
    float* sums   = (float*)(ws + 189440000L);                    //  25,600,000
    int*   src32  = (int*)  (ws + 215040000L);                    //   2,560,000
    int*   dst32  = (int*)  (ws + 217600000L);                    //   2,560,000
    int*   sp     = (int*)  (ws + 220160000L);                    //   2,560,000
    int*   dp     = (int*)  (ws + 222720000L);                    //   2,560,000
    int*   eperm  = (int*)  (ws + 225280000L);                    //   2,560,000
    int*   deg    = (int*)  (ws + 227840000L);                    //     200,704
    int*   off    = (int*)  (ws + 228040704L);                    //     200,704
    int*   cursor = (int*)  (ws + 228241408L);                    //     200,704
    int*   flag   = (int*)  (ws + 228442112L);                    //          64
    unsigned short* W1T = (unsigned short*)(ws + 228442176L);     //     589,824
    unsigned short* W2T = (unsigned short*)(ws + 229032000L);     //     196,608
    unsigned short* N1T = (unsigned short*)(ws + 229228608L);     //     393,216
    unsigned short* N2T = (unsigned short*)(ws + 229621824L);     //     196,608

    float* out = (float*)d_out;

    hipMemsetAsync(x, 0, (size_t)NNODES * HIDDEN * sizeof(float), stream);
    hipMemsetAsync(sums, 0, (size_t)NNODES * HIDDEN * sizeof(float), stream);
    hipMemsetAsync(deg, 0, 200704, stream);

    detect_kernel<<<1, 64, 0, stream>>>(ei, flag);
    normidx_kernel<<<(NEDGES + 255) / 256, 256, 0, stream>>>(ei, flag, src32, dst32);
    degree_kernel<<<(NEDGES + 255) / 256, 256, 0, stream>>>(dst32, deg);
    scan_kernel<<<1, SCAN_T, 0, stream>>>(deg, off, cursor);
    scatter_kernel<<<(NEDGES + 255) / 256, 256, 0, stream>>>(src32, dst32, cursor, sp, dp, eperm);
    encode_kernel<<<(NEDGES * 32 + 255) / 256, 256, 0, stream>>>(edge_attr, enc_w, enc_b, eperm, ef);

    transpose_kernel<<<(6 * 384 * 128 + 255) / 256, 256, 0, stream>>>(edge_w1, W1T, 384, 128, 6);
    transpose_kernel<<<(6 * 128 * 128 + 255) / 256, 256, 0, stream>>>(edge_w2, W2T, 128, 128, 6);
    transpose_kernel<<<(6 * 256 * 128 + 255) / 256, 256, 0, stream>>>(node_w1, N1T, 256, 128, 6);
    transpose_kernel<<<(6 * 128 * 128 + 255) / 256, 256, 0, stream>>>(node_w2, N2T, 128, 128, 6);

    for (int l = 0; l < NLAYERS; ++l) {
        edge_layer_mfma<<<NEDGES / 128, 256, 0, stream>>>(
            x, ef, sums, sp, dp,
            W1T + (long)l * 384 * 128, edge_b1 + (long)l * HIDDEN,
            W2T + (long)l * 128 * 128, edge_b2 + (long)l * HIDDEN);
        node_layer_mfma<<<(NNODES + 63) / 64, 256, 0, stream>>>(
            x, sums, deg,
            N1T + (long)l * 256 * 128, node_b1 + (long)l * HIDDEN,
            N2T + (long)l * 128 * 128, node_b2 + (long)l * HIDDEN);
    }

    decode_kernel<<<(NNODES * 64 + 255) / 256, 256, 0, stream>>>(x, dec_w, dec_b, out);
}

// Round 6
// 1682.515 us; speedup vs baseline: 8.2726x; 1.0787x over previous
//
#include <hip/hip_runtime.h>
#include <cstdint>

#define HIDDEN  128
#define NLAYERS 6
#define NNODES  50000
#define NEDGES  640000

typedef short short8 __attribute__((ext_vector_type(8)));
typedef float f32x4  __attribute__((ext_vector_type(4)));

// ---- bf16 <-> f32 helpers (RNE) -------------------------------------------
__device__ __forceinline__ float bf2f(unsigned short u) {
    return __uint_as_float(((unsigned int)u) << 16);
}
__device__ __forceinline__ unsigned short f2bf(float f) {
    unsigned int u = __float_as_uint(f);
    unsigned int r = u + 0x7FFFu + ((u >> 16) & 1u);
    return (unsigned short)(r >> 16);
}
__device__ __forceinline__ unsigned int pack2(float a, float b) {
    return (unsigned int)f2bf(a) | ((unsigned int)f2bf(b) << 16);
}
__device__ __forceinline__ void unpack8(uint4 v, float* f) {
    f[0] = bf2f((unsigned short)(v.x & 0xffff)); f[1] = bf2f((unsigned short)(v.x >> 16));
    f[2] = bf2f((unsigned short)(v.y & 0xffff)); f[3] = bf2f((unsigned short)(v.y >> 16));
    f[4] = bf2f((unsigned short)(v.z & 0xffff)); f[5] = bf2f((unsigned short)(v.z >> 16));
    f[6] = bf2f((unsigned short)(v.w & 0xffff)); f[7] = bf2f((unsigned short)(v.w >> 16));
}

// ---------------------------------------------------------------------------
// Index dtype detection + canonicalization
// ---------------------------------------------------------------------------
__global__ void detect_kernel(const int* __restrict__ ei, int* __restrict__ flag)
{
    int lane = threadIdx.x;
    int v = ei[2 * lane + 1];
    unsigned long long b = __ballot(v != 0);
    if (lane == 0) *flag = (b != 0ULL) ? 1 : 0;
}

__global__ void normidx_kernel(const int* __restrict__ ei, const int* __restrict__ flag,
                               int* __restrict__ s32, int* __restrict__ d32)
{
    int e = blockIdx.x * blockDim.x + threadIdx.x;
    if (e >= NEDGES) return;
    int s, d;
    if (*flag) { s = ei[e]; d = ei[NEDGES + e]; }
    else       { s = ei[2 * e]; d = ei[2 * (NEDGES + e)]; }
    s32[e] = min(max(s, 0), NNODES - 1);
    d32[e] = min(max(d, 0), NNODES - 1);
}

__global__ void degree_kernel(const int* __restrict__ dst, int* __restrict__ deg)
{
    int e = blockIdx.x * blockDim.x + threadIdx.x;
    if (e < NEDGES) atomicAdd(&deg[dst[e]], 1);
}

// ---------------------------------------------------------------------------
// Exclusive scan over deg[0..NNODES) -> off, cursor. One 1024-thread block.
// ---------------------------------------------------------------------------
#define SCAN_T 1024
__global__ void scan_kernel(const int* __restrict__ deg, int* __restrict__ off,
                            int* __restrict__ cursor)
{
    __shared__ int part[SCAN_T];
    const int t = threadIdx.x;
    const int CH = (NNODES + SCAN_T - 1) / SCAN_T;
    const int base = t * CH;
    int s = 0;
    for (int i = 0; i < CH; ++i) {
        int idx = base + i;
        if (idx < NNODES) s += deg[idx];
    }
    part[t] = s;
    __syncthreads();
    for (int d = 1; d < SCAN_T; d <<= 1) {
        int v = (t >= d) ? part[t - d] : 0;
        __syncthreads();
        part[t] += v;
        __syncthreads();
    }
    int run = (t == 0) ? 0 : part[t - 1];
    for (int i = 0; i < CH; ++i) {
        int idx = base + i;
        if (idx < NNODES) {
            off[idx] = run;
            cursor[idx] = run;
            run += deg[idx];
        }
    }
    if (t == SCAN_T - 1) off[NNODES] = run;
}

__global__ void scatter_kernel(const int* __restrict__ s32, const int* __restrict__ d32,
                               int* __restrict__ cursor,
                               int* __restrict__ sp, int* __restrict__ dp, int* __restrict__ ep)
{
    int e = blockIdx.x * blockDim.x + threadIdx.x;
    if (e >= NEDGES) return;
    int d = d32[e];
    int p = atomicAdd(&cursor[d], 1);
    sp[p] = s32[e];
    dp[p] = d;
    ep[p] = e;
}

// ---------------------------------------------------------------------------
// Weight transpose+convert: W [L][K][N] fp32 -> WT [L][N][K] bf16
// ---------------------------------------------------------------------------
__global__ void transpose_kernel(const float* __restrict__ W, unsigned short* __restrict__ WT,
                                 int K, int N, int L)
{
    long idx = (long)blockIdx.x * 256 + threadIdx.x;
    long tot = (long)L * K * N;
    if (idx >= tot) return;
    int kn = (int)(idx % ((long)K * N));
    int l  = (int)(idx / ((long)K * N));
    int k = kn / N;
    int n = kn % N;
    WT[(long)l * K * N + (long)n * K + k] = f2bf(W[idx]);
}

// ---------------------------------------------------------------------------
// Encoder into permuted layout: ef[p] = enc(ea[ep[p]])
// ---------------------------------------------------------------------------
__global__ void encode_kernel(const float* __restrict__ ea,
                              const float* __restrict__ w,
                              const float* __restrict__ b,
                              const int* __restrict__ ep,
                              unsigned short* __restrict__ ef)
{
    int idx = blockIdx.x * blockDim.x + threadIdx.x;
    int p = idx >> 5;
    if (p >= NEDGES) return;
    int e = ep[p];
    int j = (idx & 31) << 2;
    float a0 = ea[e * 3 + 0], a1 = ea[e * 3 + 1], a2 = ea[e * 3 + 2];
    float4 w0 = *(const float4*)(w + 0 * HIDDEN + j);
    float4 w1 = *(const float4*)(w + 1 * HIDDEN + j);
    float4 w2 = *(const float4*)(w + 2 * HIDDEN + j);
    float4 bb = *(const float4*)(b + j);
    ushort4 o;
    o.x = f2bf(fmaf(a0, w0.x, fmaf(a1, w1.x, fmaf(a2, w2.x, bb.x))));
    o.y = f2bf(fmaf(a0, w0.y, fmaf(a1, w1.y, fmaf(a2, w2.y, bb.y))));
    o.z = f2bf(fmaf(a0, w0.z, fmaf(a1, w1.z, fmaf(a2, w2.z, bb.z))));
    o.w = f2bf(fmaf(a0, w0.w, fmaf(a1, w1.w, fmaf(a2, w2.w, bb.w))));
    *(ushort4*)(ef + (long)p * HIDDEN + j) = o;
}

// ---------------------------------------------------------------------------
// MFMA edge layer on dst-sorted edges, factored form:
//   pre = ef @ W1c  (K=128, contiguous, MFMA)
//   H   = relu(pre + Xa[dst] + Xb[src] + b1)      (register gather-add)
//   m   = H @ W2 + b2
//   ef += m ; segmented-reduce m into sums[dst]
// 128 edges x 128 out per block, 4 waves x 32 rows.
// ---------------------------------------------------------------------------
__global__ __launch_bounds__(256, 3)
void edge_layer_mfma(const unsigned short* __restrict__ Xa,   // [N][128] bf16
                     const unsigned short* __restrict__ Xb,   // [N][128] bf16
                     unsigned short* __restrict__ ef,
                     float* __restrict__ sums,
                     const int* __restrict__ sp,
                     const int* __restrict__ dp,
                     const unsigned short* __restrict__ W1T,  // [128][384] bf16; W1c at k+256
                     const float* __restrict__ b1,
                     const unsigned short* __restrict__ W2T,  // [128][128] bf16
                     const float* __restrict__ b2)
{
    // 0      .. 34816 : Hs (stride 136) / As (stride 40) aliased
    // 34816  .. 45056 : Bs (stride 40)
    __shared__ __align__(16) unsigned char buf[45056];
    unsigned short* As = (unsigned short*)buf;
    unsigned short* Hs = (unsigned short*)buf;
    unsigned short* Bs = (unsigned short*)(buf + 34816);
    __shared__ int dv[128];
    __shared__ int sv[128];

    const int tid = threadIdx.x;
    const long eb = (long)blockIdx.x * 128;
    if (tid < 128) dv[tid]       = dp[eb + tid];
    else           sv[tid - 128] = sp[eb + tid - 128];

    const int lane = tid & 63;
    const int wv   = tid >> 6;
    const int mn   = lane & 15;
    const int q    = lane >> 4;
    const int rr   = tid >> 1;          // staging row 0..127
    const int o    = (tid & 1) << 4;    // 16-short half: 0 or 16
    const int bn   = tid >> 1;          // Bs row
    const int bk   = (tid & 1) << 4;

    __syncthreads();

    f32x4 acc[2][8];
#pragma unroll
    for (int h = 0; h < 2; ++h)
#pragma unroll
        for (int t = 0; t < 8; ++t) acc[h][t] = (f32x4)0.0f;

    uint4 pa0, pa1, pw0, pw1;
    {   // chunk 0 loads
        const unsigned short* epp = ef + (eb + rr) * HIDDEN + o;
        pa0 = *(const uint4*)epp;
        pa1 = *(const uint4*)(epp + 8);
        const unsigned short* wp = W1T + (long)bn * 384 + 256 + bk;
        pw0 = *(const uint4*)wp;
        pw1 = *(const uint4*)(wp + 8);
    }

    // ---- GEMM1: ef @ W1c, 4 k-steps of 32 ----
    for (int c = 0; c < 4; ++c) {
        *(uint4*)&As[rr * 40 + o]     = pa0;
        *(uint4*)&As[rr * 40 + o + 8] = pa1;
        *(uint4*)&Bs[bn * 40 + bk]     = pw0;
        *(uint4*)&Bs[bn * 40 + bk + 8] = pw1;
        __syncthreads();

        if (c + 1 < 4) {
            const int cn = c + 1;
            const unsigned short* epp = ef + (eb + rr) * HIDDEN + (cn << 5) + o;
            pa0 = *(const uint4*)epp;
            pa1 = *(const uint4*)(epp + 8);
            const unsigned short* wp = W1T + (long)bn * 384 + 256 + (cn << 5) + bk;
            pw0 = *(const uint4*)wp;
            pw1 = *(const uint4*)(wp + 8);
        }

        short8 af0 = *(short8*)&As[(wv * 32 + mn) * 40 + (q << 3)];
        short8 af1 = *(short8*)&As[(wv * 32 + 16 + mn) * 40 + (q << 3)];
#pragma unroll
        for (int nt = 0; nt < 8; ++nt) {
            short8 bf = *(short8*)&Bs[(nt * 16 + mn) * 40 + (q << 3)];
            acc[0][nt] = __builtin_amdgcn_mfma_f32_16x16x32_bf16(af0, bf, acc[0][nt], 0, 0, 0);
            acc[1][nt] = __builtin_amdgcn_mfma_f32_16x16x32_bf16(af1, bf, acc[1][nt], 0, 0, 0);
        }
        __syncthreads();
    }

    // ---- H = relu(acc + Xa[dst] + Xb[src] + b1) -> Hs bf16 ----
    // rows are quarter-wave-uniform -> 16 lanes read 32B contiguous (coalesced)
#pragma unroll
    for (int h = 0; h < 2; ++h)
#pragma unroll
        for (int r = 0; r < 4; ++r) {
            const int row = wv * 32 + h * 16 + q * 4 + r;
            const long ba = (long)dv[row] * HIDDEN;
            const long bb = (long)sv[row] * HIDDEN;
#pragma unroll
            for (int nt = 0; nt < 8; ++nt) {
                const int col = nt * 16 + mn;
                float add = bf2f(Xa[ba + col]) + bf2f(Xb[bb + col]) + b1[col];
                float hv = fmaxf(acc[h][nt][r] + add, 0.0f);
                Hs[row * 136 + col] = f2bf(hv);
            }
        }

    // ---- GEMM2: 4 k-steps of 32 ----
    f32x4 acc2[2][8];
#pragma unroll
    for (int h = 0; h < 2; ++h)
#pragma unroll
        for (int t = 0; t < 8; ++t) acc2[h][t] = (f32x4)0.0f;
    {
        const unsigned short* wp = W2T + (long)bn * 128 + bk;
        pw0 = *(const uint4*)wp;
        pw1 = *(const uint4*)(wp + 8);
    }
    for (int c = 0; c < 4; ++c) {
        *(uint4*)&Bs[bn * 40 + bk]     = pw0;
        *(uint4*)&Bs[bn * 40 + bk + 8] = pw1;
        __syncthreads();
        if (c + 1 < 4) {
            const unsigned short* wp = W2T + (long)bn * 128 + ((c + 1) << 5) + bk;
            pw0 = *(const uint4*)wp;
            pw1 = *(const uint4*)(wp + 8);
        }
        short8 af0 = *(short8*)&Hs[(wv * 32 + mn) * 136 + (c << 5) + (q << 3)];
        short8 af1 = *(short8*)&Hs[(wv * 32 + 16 + mn) * 136 + (c << 5) + (q << 3)];
#pragma unroll
        for (int nt = 0; nt < 8; ++nt) {
            short8 bf = *(short8*)&Bs[(nt * 16 + mn) * 40 + (q << 3)];
            acc2[0][nt] = __builtin_amdgcn_mfma_f32_16x16x32_bf16(af0, bf, acc2[0][nt], 0, 0, 0);
            acc2[1][nt] = __builtin_amdgcn_mfma_f32_16x16x32_bf16(af1, bf, acc2[1][nt], 0, 0, 0);
        }
        __syncthreads();
    }

    // ---- m = acc2 + b2 -> Hs bf16 (wave-private rows) ----
#pragma unroll
    for (int h = 0; h < 2; ++h)
#pragma unroll
        for (int nt = 0; nt < 8; ++nt) {
            float b2v = b2[nt * 16 + mn];
#pragma unroll
            for (int r = 0; r < 4; ++r) {
                Hs[(wv * 32 + h * 16 + q * 4 + r) * 136 + nt * 16 + mn] = f2bf(acc2[h][nt][r] + b2v);
            }
        }
    __syncthreads();

    // ---- ef += m (coalesced, full rows) ----
    {
        const int row = tid >> 1;
        const int ch  = (tid & 1) << 6;
        unsigned short* ep_ = ef + (eb + row) * HIDDEN + ch;
        const unsigned short* hp = &Hs[row * 136 + ch];
#pragma unroll
        for (int i = 0; i < 8; ++i) {
            uint4 mh = *(uint4*)(hp + (i << 3));
            uint4 eo = *(const uint4*)(ep_ + (i << 3));
            float m[8], e[8];
            unpack8(mh, m);
            unpack8(eo, e);
            uint4 nw;
            nw.x = pack2(e[0] + m[0], e[1] + m[1]);
            nw.y = pack2(e[2] + m[2], e[3] + m[3]);
            nw.z = pack2(e[4] + m[4], e[5] + m[5]);
            nw.w = pack2(e[6] + m[6], e[7] + m[7]);
            *(uint4*)(ep_ + (i << 3)) = nw;
        }
    }

    // ---- segmented reduction by dst-run: one atomic row per run ----
    {
        const int cp = (tid & 63) << 1;
        const int qr = tid >> 6;
        float s0 = 0.0f, s1 = 0.0f;
        int cur = dv[qr * 32];
        for (int r = 0; r < 32; ++r) {
            const int row = qr * 32 + r;
            const int d = dv[row];
            if (d != cur) {
                atomicAdd(&sums[(long)cur * HIDDEN + cp], s0);
                atomicAdd(&sums[(long)cur * HIDDEN + cp + 1], s1);
                s0 = 0.0f; s1 = 0.0f;
                cur = d;
            }
            unsigned int u = *(unsigned int*)&Hs[row * 136 + cp];
            s0 += bf2f((unsigned short)(u & 0xffff));
            s1 += bf2f((unsigned short)(u >> 16));
        }
        atomicAdd(&sums[(long)cur * HIDDEN + cp], s0);
        atomicAdd(&sums[(long)cur * HIDDEN + cp + 1], s1);
    }
}

// ---------------------------------------------------------------------------
// MFMA node layer. 64 nodes x 128 out per block. Also:
//   - zeros its sums rows after consuming them
//   - computes Xa = xnew @ W1a(l+1), Xb = xnew @ W1b(l+1) for the next layer
// ---------------------------------------------------------------------------
__global__ __launch_bounds__(256, 4)
void node_layer_mfma(float* __restrict__ x,
                     float* __restrict__ sums,
                     const int* __restrict__ deg,
                     const unsigned short* __restrict__ N1T,  // [128][256] bf16
                     const float* __restrict__ b1,
                     const unsigned short* __restrict__ N2T,  // [128][128] bf16
                     const float* __restrict__ b2,
                     const unsigned short* __restrict__ W1Tn, // [128][384] next layer (or null)
                     unsigned short* __restrict__ Xa,
                     unsigned short* __restrict__ Xb)
{
    __shared__ __align__(16) unsigned short As[64 * 40];
    __shared__ __align__(16) unsigned short Bs[128 * 40];
    __shared__ __align__(16) unsigned short Hs[64 * 136];
    __shared__ float cInv[64];

    const int tid = threadIdx.x;
    const long n0 = (long)blockIdx.x * 64;
    if (tid < 64) {
        long n = n0 + tid;
        cInv[tid] = (n < NNODES) ? 1.0f / fmaxf((float)deg[n], 1.0f) : 0.0f;
    }

    const int lane = tid & 63;
    const int wv   = tid >> 6;
    const int mn   = lane & 15;
    const int q    = lane >> 4;
    const int srow = tid >> 2;
    const int sseg = tid & 3;
    const int bn   = tid >> 1;
    const int bk   = (tid & 1) << 4;

    long nr = n0 + srow;
    if (nr >= NNODES) nr = NNODES - 1;

    __syncthreads();

    f32x4 acc[8];
#pragma unroll
    for (int t = 0; t < 8; ++t) acc[t] = (f32x4)0.0f;

    float4 pa0, pa1;
    uint4 pb0, pb1;
    {
        const float* spx = x + nr * HIDDEN + (sseg << 3);
        pa0 = *(const float4*)spx;
        pa1 = *(const float4*)(spx + 4);
        const unsigned short* wp = N1T + (long)bn * 256 + bk;
        pb0 = *(const uint4*)wp;
        pb1 = *(const uint4*)(wp + 8);
    }
    float scCur = 1.0f;
    for (int c = 0; c < 8; ++c) {
        {
            uint4 w;
            w.x = pack2(pa0.x * scCur, pa0.y * scCur); w.y = pack2(pa0.z * scCur, pa0.w * scCur);
            w.z = pack2(pa1.x * scCur, pa1.y * scCur); w.w = pack2(pa1.z * scCur, pa1.w * scCur);
            *(uint4*)&As[srow * 40 + (sseg << 3)] = w;
        }
        *(uint4*)&Bs[bn * 40 + bk]     = pb0;
        *(uint4*)&Bs[bn * 40 + bk + 8] = pb1;
        __syncthreads();
        if (c + 1 < 8) {
            const int cn = c + 1;
            const float* base = (cn < 4) ? x : sums;
            scCur = (cn < 4) ? 1.0f : cInv[srow];
            const float* spx = base + nr * HIDDEN + ((cn & 3) << 5) + (sseg << 3);
            pa0 = *(const float4*)spx;
            pa1 = *(const float4*)(spx + 4);
            const unsigned short* wp = N1T + (long)bn * 256 + (cn << 5) + bk;
            pb0 = *(const uint4*)wp;
            pb1 = *(const uint4*)(wp + 8);
        }
        short8 af = *(short8*)&As[(wv * 16 + mn) * 40 + (q << 3)];
#pragma unroll
        for (int nt = 0; nt < 8; ++nt) {
            short8 bf = *(short8*)&Bs[(nt * 16 + mn) * 40 + (q << 3)];
            acc[nt] = __builtin_amdgcn_mfma_f32_16x16x32_bf16(af, bf, acc[nt], 0, 0, 0);
        }
        __syncthreads();
    }

    // zero own sums rows for the next layer
    {
        long row = n0 + srow;
        if (row < NNODES) {
            float4 z = make_float4(0.f, 0.f, 0.f, 0.f);
            float* p = sums + row * HIDDEN + (sseg << 5);
#pragma unroll
            for (int i = 0; i < 8; ++i) ((float4*)p)[i] = z;
        }
    }

#pragma unroll
    for (int nt = 0; nt < 8; ++nt) {
        float b1v = b1[nt * 16 + mn];
#pragma unroll
        for (int r = 0; r < 4; ++r) {
            float hv = fmaxf(acc[nt][r] + b1v, 0.0f);
            Hs[(wv * 16 + q * 4 + r) * 136 + nt * 16 + mn] = f2bf(hv);
        }
    }

    f32x4 acc2[8];
#pragma unroll
    for (int t = 0; t < 8; ++t) acc2[t] = (f32x4)0.0f;
    {
        const unsigned short* wp = N2T + (long)bn * 128 + bk;
        pb0 = *(const uint4*)wp;
        pb1 = *(const uint4*)(wp + 8);
    }
    for (int c = 0; c < 4; ++c) {
        *(uint4*)&Bs[bn * 40 + bk]     = pb0;
        *(uint4*)&Bs[bn * 40 + bk + 8] = pb1;
        __syncthreads();
        if (c + 1 < 4) {
            const unsigned short* wp = N2T + (long)bn * 128 + ((c + 1) << 5) + bk;
            pb0 = *(const uint4*)wp;
            pb1 = *(const uint4*)(wp + 8);
        }
        short8 af = *(short8*)&Hs[(wv * 16 + mn) * 136 + (c << 5) + (q << 3)];
#pragma unroll
        for (int nt = 0; nt < 8; ++nt) {
            short8 bf = *(short8*)&Bs[(nt * 16 + mn) * 40 + (q << 3)];
            acc2[nt] = __builtin_amdgcn_mfma_f32_16x16x32_bf16(af, bf, acc2[nt], 0, 0, 0);
        }
        __syncthreads();
    }

    // ---- xnew = x + acc2 + b2 (exact fp32); stage xnew bf16 into Hs ----
#pragma unroll
    for (int nt = 0; nt < 8; ++nt) {
        float b2v = b2[nt * 16 + mn];
#pragma unroll
        for (int r = 0; r < 4; ++r) {
            long row = n0 + wv * 16 + q * 4 + r;
            float xn = 0.0f;
            if (row < NNODES) {
                float* p = x + row * HIDDEN + nt * 16 + mn;
                xn = *p + acc2[nt][r] + b2v;
                *p = xn;
            }
            Hs[(wv * 16 + q * 4 + r) * 136 + nt * 16 + mn] = f2bf(xn);
        }
    }

    // ---- Xa/Xb for next layer: xnew @ W1a / W1b (K=128 each) ----
    if (W1Tn) {
#pragma unroll
        for (int half = 0; half < 2; ++half) {
            f32x4 accN[8];
#pragma unroll
            for (int t = 0; t < 8; ++t) accN[t] = (f32x4)0.0f;
            const int kbase = half << 7;   // 0: W1a, 128: W1b
            {
                const unsigned short* wp = W1Tn + (long)bn * 384 + kbase + bk;
                pb0 = *(const uint4*)wp;
                pb1 = *(const uint4*)(wp + 8);
            }
            for (int c = 0; c < 4; ++c) {
                *(uint4*)&Bs[bn * 40 + bk]     = pb0;
                *(uint4*)&Bs[bn * 40 + bk + 8] = pb1;
                __syncthreads();
                if (c + 1 < 4) {
                    const unsigned short* wp = W1Tn + (long)bn * 384 + kbase + ((c + 1) << 5) + bk;
                    pb0 = *(const uint4*)wp;
                    pb1 = *(const uint4*)(wp + 8);
                }
                short8 af = *(short8*)&Hs[(wv * 16 + mn) * 136 + (c << 5) + (q << 3)];
#pragma unroll
                for (int nt = 0; nt < 8; ++nt) {
                    short8 bf = *(short8*)&Bs[(nt * 16 + mn) * 40 + (q << 3)];
                    accN[nt] = __builtin_amdgcn_mfma_f32_16x16x32_bf16(af, bf, accN[nt], 0, 0, 0);
                }
                __syncthreads();
            }
            unsigned short* Xout = half ? Xb : Xa;
#pragma unroll
            for (int nt = 0; nt < 8; ++nt) {
#pragma unroll
                for (int r = 0; r < 4; ++r) {
                    long row = n0 + wv * 16 + q * 4 + r;
                    if (row < NNODES) {
                        Xout[row * HIDDEN + nt * 16 + mn] = f2bf(accN[nt][r]);
                    }
                }
            }
        }
    }
}

// ---------------------------------------------------------------------------
// Decoder + row L2-normalize (one wave per node)
// ---------------------------------------------------------------------------
__global__ void decode_kernel(const float* __restrict__ x,
                              const float* __restrict__ w,
                              const float* __restrict__ b,
                              float* __restrict__ out)
{
    int gid = blockIdx.x * blockDim.x + threadIdx.x;
    int node = gid >> 6;
    int lane = threadIdx.x & 63;
    if (node >= NNODES) return;
    float a0 = 0.f, a1 = 0.f, a2 = 0.f;
#pragma unroll
    for (int k = lane; k < HIDDEN; k += 64) {
        float xv = x[(long)node * HIDDEN + k];
        a0 = fmaf(xv, w[k * 3 + 0], a0);
        a1 = fmaf(xv, w[k * 3 + 1], a1);
        a2 = fmaf(xv, w[k * 3 + 2], a2);
    }
#pragma unroll
    for (int off = 32; off > 0; off >>= 1) {
        a0 += __shfl_down(a0, off);
        a1 += __shfl_down(a1, off);
        a2 += __shfl_down(a2, off);
    }
    if (lane == 0) {
        a0 += b[0]; a1 += b[1]; a2 += b[2];
        float nrm = sqrtf(a0 * a0 + a1 * a1 + a2 * a2);
        float inv = 1.0f / fmaxf(nrm, 1e-12f);
        out[(long)node * 3 + 0] = a0 * inv;
        out[(long)node * 3 + 1] = a1 * inv;
        out[(long)node * 3 + 2] = a2 * inv;
    }
}

// ---------------------------------------------------------------------------
extern "C" void kernel_launch(void* const* d_in, const int* in_sizes, int n_in,
                              void* d_out, int out_size, void* d_ws, size_t ws_size,
                              hipStream_t stream)
{
    const float* edge_attr = (const float*)d_in[1];
    const int*   ei        = (const int*)d_in[2];
    const float* enc_w     = (const float*)d_in[3];
    const float* enc_b     = (const float*)d_in[4];
    const float* dec_w     = (const float*)d_in[5];
    const float* dec_b     = (const float*)d_in[6];
    const float* edge_w1   = (const float*)d_in[7];
    const float* edge_b1   = (const float*)d_in[8];
    const float* edge_w2   = (const float*)d_in[9];
    const float* edge_b2   = (const float*)d_in[10];
    const float* node_w1   = (const float*)d_in[11];
    const float* node_b1   = (const float*)d_in[12];
    const float* node_w2   = (const float*)d_in[13];
    const float* node_b2   = (const float*)d_in[14];

    // workspace layout (bytes), 16B-aligned, total ~255.4 MB
    char* ws = (char*)d_ws;
    unsigned short* ef  = (unsigned short*)(ws);                  // 163,840,000
    float* x      = (float*)(ws + 163840000L);                    //  25,600,000
    float* sums   = (float*)(ws + 189440000L);                    //  25,600,000
    int*   src32  = (int*)  (ws + 215040000L);                    //   2,560,000
    int*   dst32  = (int*)  (ws + 217600000L);                    //   2,560,000
    int*   sp     = (int*)  (ws + 220160000L);                    //   2,560,000
    int*   dp     = (int*)  (ws + 222720000L);                    //   2,560,000
    int*   eperm  = (int*)  (ws + 225280000L);                    //   2,560,000
    int*   deg    = (int*)  (ws + 227840000L);                    //     200,704
    int*   off    = (int*)  (ws + 228040704L);                    //     200,704
    int*   cursor = (int*)  (ws + 228241408L);                    //     200,704
    int*   flag   = (int*)  (ws + 228442112L);                    //          64
    unsigned short* W1T = (unsigned short*)(ws + 228442176L);     //     589,824
    unsigned short* W2T = (unsigned short*)(ws + 229032000L);     //     196,608
    unsigned short* N1T = (unsigned short*)(ws + 229228608L);     //     393,216
    unsigned short* N2T = (unsigned short*)(ws + 229621824L);     //     196,608
    unsigned short* Xa  = (unsigned short*)(ws + 229818432L);     //  12,800,000
    unsigned short* Xb  = (unsigned short*)(ws + 242618432L);     //  12,800,000
    // end: 255,418,432

    float* out = (float*)d_out;

    hipMemsetAsync(x, 0, (size_t)NNODES * HIDDEN * sizeof(float), stream);
    hipMemsetAsync(sums, 0, (size_t)NNODES * HIDDEN * sizeof(float), stream);
    hipMemsetAsync(deg, 0, 200704, stream);
    hipMemsetAsync(Xa, 0, 25600000, stream);   // Xa + Xb (contiguous)

    detect_kernel<<<1, 64, 0, stream>>>(ei, flag);
    normidx_kernel<<<(NEDGES + 255) / 256, 256, 0, stream>>>(ei, flag, src32, dst32);
    degree_kernel<<<(NEDGES + 255) / 256, 256, 0, stream>>>(dst32, deg);
    scan_kernel<<<1, SCAN_T, 0, stream>>>(deg, off, cursor);
    scatter_kernel<<<(NEDGES + 255) / 256, 256, 0, stream>>>(src32, dst32, cursor, sp, dp, eperm);
    encode_kernel<<<(NEDGES * 32 + 255) / 256, 256, 0, stream>>>(edge_attr, enc_w, enc_b, eperm, ef);

    transpose_kernel<<<(6 * 384 * 128 + 255) / 256, 256, 0, stream>>>(edge_w1, W1T, 384, 128, 6);
    transpose_kernel<<<(6 * 128 * 128 + 255) / 256, 256, 0, stream>>>(edge_w2, W2T, 128, 128, 6);
    transpose_kernel<<<(6 * 256 * 128 + 255) / 256, 256, 0, stream>>>(node_w1, N1T, 256, 128, 6);
    transpose_kernel<<<(6 * 128 * 128 + 255) / 256, 256, 0, stream>>>(node_w2, N2T, 128, 128, 6);

    for (int l = 0; l < NLAYERS; ++l) {
        edge_layer_mfma<<<NEDGES / 128, 256, 0, stream>>>(
            Xa, Xb, ef, sums, sp, dp,
            W1T + (long)l * 384 * 128, edge_b1 + (long)l * HIDDEN,
            W2T + (long)l * 128 * 128, edge_b2 + (long)l * HIDDEN);
        const unsigned short* w1next = (l + 1 < NLAYERS) ? (W1T + (long)(l + 1) * 384 * 128) : nullptr;
        node_layer_mfma<<<(NNODES + 63) / 64, 256, 0, stream>>>(
            x, sums, deg,
            N1T + (long)l * 256 * 128, node_b1 + (long)l * HIDDEN,
            N2T + (long)l * 128 * 128, node_b2 + (long)l * HIDDEN,
            w1next, Xa, Xb);
    }

    decode_kernel<<<(NNODES * 64 + 255) / 256, 256, 0, stream>>>(x, dec_w, dec_b, out);
}